// Round 1
// baseline (2191.534 us; speedup 1.0000x reference)
//
#include <hip/hip_runtime.h>

#define N_NODES 50000
#define N_EDGES 600000
#define D 128
#define BM 32

// ---------------- SpMM scatter: agg[rows[e]] += vals[e] * x[cols[e]] ----------------
// 32 lanes per edge, each lane handles 4 consecutive floats (float4 gather, 4 atomics).
__global__ __launch_bounds__(256) void spmm_scatter(
    const int* __restrict__ rows, const int* __restrict__ cols,
    const float* __restrict__ vals, const float* __restrict__ x,
    float* __restrict__ agg, int nE)
{
    int g = blockIdx.x * 256 + threadIdx.x;
    int e = g >> 5;
    if (e >= nE) return;
    int q = g & 31;
    int r = rows[e];
    int c = cols[e];
    float v = vals[e];
    float4 xv = *reinterpret_cast<const float4*>(x + (size_t)c * D + (size_t)q * 4);
    float* ap = agg + (size_t)r * D + (size_t)q * 4;
    atomicAdd(ap + 0, v * xv.x);
    atomicAdd(ap + 1, v * xv.y);
    atomicAdd(ap + 2, v * xv.z);
    atomicAdd(ap + 3, v * xv.w);
}

// ---------------- fused 3xGEMM + bias + LayerNorm + ReLU ----------------
// Block: 256 threads, BM=32 node-rows. Each thread: cols (l, l+64), rows w+4i (i=0..7).
// W staged in LDS with XOR swizzle (T2) so the lane-per-row ds_read_b128 is conflict-free.
// Each output row lives entirely in one wave -> LN via 64-lane shfl_xor reduction.
__global__ __launch_bounds__(256) void gemm_ln_relu(
    const float* __restrict__ x, const float* __restrict__ agg_in,
    const float* __restrict__ agg_out,
    const float* __restrict__ Ws, const float* __restrict__ Wi,
    const float* __restrict__ Wo, const float* __restrict__ b,
    const float* __restrict__ gamma, const float* __restrict__ beta,
    float* __restrict__ out, int n)
{
    __shared__ float4 Wl[D * (D / 4)];   // 128 rows x 32 float4 = 64 KB (swizzled)
    __shared__ float4 Xl[BM * (D / 4)];  // 32 rows x 32 float4 = 16 KB

    const int t = threadIdx.x;
    const int l = t & 63;   // lane
    const int w = t >> 6;   // wave 0..3
    const int base = blockIdx.x * BM;

    const int j0 = l;
    const int j1 = l + 64;

    float acc0[8], acc1[8];
    const float bj0 = b[j0], bj1 = b[j1];
#pragma unroll
    for (int i = 0; i < 8; ++i) { acc0[i] = bj0; acc1[i] = bj1; }

    const float* srcs[3] = { x, agg_in, agg_out };
    const float* wms[3]  = { Ws, Wi, Wo };

#pragma unroll
    for (int s = 0; s < 3; ++s) {
        const float4* src4 = reinterpret_cast<const float4*>(srcs[s]);
        const float4* w4   = reinterpret_cast<const float4*>(wms[s]);
        __syncthreads();  // protect previous iteration's LDS reads
        // stage W (4096 float4), XOR-swizzled: slot k4 ^ (row & 7)
#pragma unroll
        for (int it = 0; it < 16; ++it) {
            int gi = t + 256 * it;
            int j = gi >> 5, k4 = gi & 31;
            Wl[j * 32 + (k4 ^ (j & 7))] = w4[gi];
        }
        // stage X tile (1024 float4), linear
#pragma unroll
        for (int it = 0; it < 4; ++it) {
            int gi = t + 256 * it;
            int m = gi >> 5, k4 = gi & 31;
            int node = base + m;
            float4 v = (node < n) ? src4[(size_t)node * 32 + k4]
                                  : make_float4(0.f, 0.f, 0.f, 0.f);
            Xl[m * 32 + k4] = v;
        }
        __syncthreads();

        const int sw = j0 & 7;  // (j1 & 7) == (j0 & 7)
#pragma unroll 8
        for (int k4 = 0; k4 < 32; ++k4) {
            float4 w0 = Wl[j0 * 32 + (k4 ^ sw)];
            float4 w1 = Wl[j1 * 32 + (k4 ^ sw)];
#pragma unroll
            for (int i = 0; i < 8; ++i) {
                float4 xv = Xl[(w + 4 * i) * 32 + k4];  // wave-uniform -> broadcast
                acc0[i] += xv.x * w0.x + xv.y * w0.y + xv.z * w0.z + xv.w * w0.w;
                acc1[i] += xv.x * w1.x + xv.y * w1.y + xv.z * w1.z + xv.w * w1.w;
            }
        }
    }

    // ---- LayerNorm + ReLU + store (row fully inside this wave) ----
    const float g0 = gamma[j0], g1 = gamma[j1];
    const float be0 = beta[j0], be1 = beta[j1];
#pragma unroll
    for (int i = 0; i < 8; ++i) {
        int node = base + w + 4 * i;
        float s  = acc0[i] + acc1[i];
        float ss = acc0[i] * acc0[i] + acc1[i] * acc1[i];
#pragma unroll
        for (int off = 32; off; off >>= 1) {
            s  += __shfl_xor(s, off);
            ss += __shfl_xor(ss, off);
        }
        float mu   = s * (1.0f / D);
        float var  = ss * (1.0f / D) - mu * mu;
        float rstd = rsqrtf(var + 1e-5f);
        if (node < n) {
            float y0 = (acc0[i] - mu) * rstd * g0 + be0;
            float y1 = (acc1[i] - mu) * rstd * g1 + be1;
            out[(size_t)node * D + j0] = fmaxf(y0, 0.f);
            out[(size_t)node * D + j1] = fmaxf(y1, 0.f);
        }
    }
}

extern "C" void kernel_launch(void* const* d_in, const int* in_sizes, int n_in,
                              void* d_out, int out_size, void* d_ws, size_t ws_size,
                              hipStream_t stream) {
    const float* x     = (const float*)d_in[0];
    const int*   ir    = (const int*)  d_in[1];
    const int*   icoln = (const int*)  d_in[2];
    const float* ival  = (const float*)d_in[3];
    const int*   orow  = (const int*)  d_in[4];
    const int*   ocol  = (const int*)  d_in[5];
    const float* oval  = (const float*)d_in[6];
    const float* Ws    = (const float*)d_in[7];
    const float* b     = (const float*)d_in[8];
    const float* Wi    = (const float*)d_in[9];
    const float* Wo    = (const float*)d_in[10];
    const float* gamma = (const float*)d_in[11];
    const float* beta  = (const float*)d_in[12];
    float* out = (float*)d_out;

    float* agg_in  = (float*)d_ws;
    float* agg_out = agg_in + (size_t)N_NODES * D;

    hipMemsetAsync(d_ws, 0, 2 * (size_t)N_NODES * D * sizeof(float), stream);

    const int eblocks = (N_EDGES * 32 + 255) / 256;  // 75000
    spmm_scatter<<<eblocks, 256, 0, stream>>>(ir, icoln, ival, x, agg_in, N_EDGES);
    spmm_scatter<<<eblocks, 256, 0, stream>>>(orow, ocol, oval, x, agg_out, N_EDGES);

    const int gblocks = (N_NODES + BM - 1) / BM;  // 1563
    gemm_ln_relu<<<gblocks, 256, 0, stream>>>(x, agg_in, agg_out, Ws, Wi, Wo,
                                              b, gamma, beta, out, N_NODES);
}

// Round 2
// 601.255 us; speedup vs baseline: 3.6449x; 3.6449x over previous
//
#include <hip/hip_runtime.h>

#define N_NODES 50000
#define N_EDGES 600000
#define D 128
#define BM 32
#define NT (2 * N_NODES)          // 100000 combined rows (in | out)
#define NE2 (2 * N_EDGES)         // 1200000 combined edges

// ================= CSR-build path (no fp32 atomics) =================

// Histogram of combined rows into cnt[0..NT)
__global__ __launch_bounds__(256) void hist_rows(
    const int* __restrict__ ir, const int* __restrict__ orow, int* __restrict__ cnt)
{
    int e = blockIdx.x * 256 + threadIdx.x;
    if (e < N_EDGES)      atomicAdd(&cnt[ir[e]], 1);
    else if (e < NE2)     atomicAdd(&cnt[N_NODES + orow[e - N_EDGES]], 1);
}

// Exclusive scan over cnt[0..NT) -> row_ptr[0..NT], and cursor[j] = row_ptr[j].
// Single block of 1024 threads; each thread owns a contiguous chunk.
#define CHUNK 98  // ceil(100000/1024)
__global__ __launch_bounds__(1024) void scan_counts(
    int* __restrict__ cnt /*in: counts, out: cursor*/, int* __restrict__ row_ptr)
{
    __shared__ int sbuf[1024];
    const int i = threadIdx.x;
    const int c0 = i * CHUNK;
    const int c1 = min(c0 + CHUNK, NT);

    int run = 0;
    for (int j = c0; j < c1; ++j) run += cnt[j];

    sbuf[i] = run;
    __syncthreads();
    // Hillis-Steele inclusive scan
    for (int off = 1; off < 1024; off <<= 1) {
        int v = (i >= off) ? sbuf[i - off] : 0;
        __syncthreads();
        sbuf[i] += v;
        __syncthreads();
    }
    int pos = sbuf[i] - run;  // exclusive prefix for this thread's chunk
    for (int j = c0; j < c1; ++j) {
        int c = cnt[j];
        row_ptr[j] = pos;
        cnt[j] = pos;     // cursor
        pos += c;
    }
    if (i == 1023) row_ptr[NT] = sbuf[1023];
}

// Place each edge's (col, val) into its row bucket.
__global__ __launch_bounds__(256) void scatter_edges(
    const int* __restrict__ ir, const int* __restrict__ icol, const float* __restrict__ ival,
    const int* __restrict__ orow, const int* __restrict__ ocol, const float* __restrict__ oval,
    int* __restrict__ cursor, int* __restrict__ colp, float* __restrict__ valp)
{
    int e = blockIdx.x * 256 + threadIdx.x;
    int r, c; float v;
    if (e < N_EDGES)      { r = ir[e];                       c = icol[e];            v = ival[e]; }
    else if (e < NE2)     { r = N_NODES + orow[e - N_EDGES]; c = ocol[e - N_EDGES];  v = oval[e - N_EDGES]; }
    else return;
    int pos = atomicAdd(&cursor[r], 1);
    colp[pos] = c;
    valp[pos] = v;
}

// One wave per combined row: agg[r] = sum_e val[e] * x[col[e]].
// Lane holds 2 consecutive floats -> each edge is one coalesced 512B read.
__global__ __launch_bounds__(256) void gather_rows(
    const int* __restrict__ row_ptr, const int* __restrict__ colp,
    const float* __restrict__ valp, const float* __restrict__ x,
    float* __restrict__ agg)
{
    const int wv = blockIdx.x * 4 + (threadIdx.x >> 6);
    if (wv >= NT) return;
    const int lane = threadIdx.x & 63;
    const int s = row_ptr[wv];
    const int e = row_ptr[wv + 1];

    float ax = 0.f, ay = 0.f;
    const float* xb = x + lane * 2;

    int i = s;
    for (; i + 1 < e; i += 2) {   // 2-edge unroll for ILP
        int   ca = colp[i],     cb = colp[i + 1];
        float va = valp[i],     vb = valp[i + 1];
        float2 xa = *reinterpret_cast<const float2*>(xb + (size_t)ca * D);
        float2 xc = *reinterpret_cast<const float2*>(xb + (size_t)cb * D);
        ax += va * xa.x + vb * xc.x;
        ay += va * xa.y + vb * xc.y;
    }
    if (i < e) {
        int c = colp[i]; float v = valp[i];
        float2 xa = *reinterpret_cast<const float2*>(xb + (size_t)c * D);
        ax += v * xa.x;
        ay += v * xa.y;
    }
    float2 r = make_float2(ax, ay);
    *reinterpret_cast<float2*>(agg + (size_t)wv * D + lane * 2) = r;
}

// ================= fallback: atomic scatter SpMM =================
__global__ __launch_bounds__(256) void spmm_scatter(
    const int* __restrict__ rows, const int* __restrict__ cols,
    const float* __restrict__ vals, const float* __restrict__ x,
    float* __restrict__ agg, int nE)
{
    int g = blockIdx.x * 256 + threadIdx.x;
    int e = g >> 5;
    if (e >= nE) return;
    int q = g & 31;
    int r = rows[e];
    int c = cols[e];
    float v = vals[e];
    float4 xv = *reinterpret_cast<const float4*>(x + (size_t)c * D + (size_t)q * 4);
    float* ap = agg + (size_t)r * D + (size_t)q * 4;
    atomicAdd(ap + 0, v * xv.x);
    atomicAdd(ap + 1, v * xv.y);
    atomicAdd(ap + 2, v * xv.z);
    atomicAdd(ap + 3, v * xv.w);
}

// ================= fused 3xGEMM + bias + LayerNorm + ReLU =================
__global__ __launch_bounds__(256) void gemm_ln_relu(
    const float* __restrict__ x, const float* __restrict__ agg_in,
    const float* __restrict__ agg_out,
    const float* __restrict__ Ws, const float* __restrict__ Wi,
    const float* __restrict__ Wo, const float* __restrict__ b,
    const float* __restrict__ gamma, const float* __restrict__ beta,
    float* __restrict__ out, int n)
{
    __shared__ float4 Wl[D * (D / 4)];   // 64 KB (swizzled)
    __shared__ float4 Xl[BM * (D / 4)];  // 16 KB

    const int t = threadIdx.x;
    const int l = t & 63;
    const int w = t >> 6;
    const int base = blockIdx.x * BM;

    const int j0 = l;
    const int j1 = l + 64;

    float acc0[8], acc1[8];
    const float bj0 = b[j0], bj1 = b[j1];
#pragma unroll
    for (int i = 0; i < 8; ++i) { acc0[i] = bj0; acc1[i] = bj1; }

    const float* srcs[3] = { x, agg_in, agg_out };
    const float* wms[3]  = { Ws, Wi, Wo };

#pragma unroll
    for (int s = 0; s < 3; ++s) {
        const float4* src4 = reinterpret_cast<const float4*>(srcs[s]);
        const float4* w4   = reinterpret_cast<const float4*>(wms[s]);
        __syncthreads();
#pragma unroll
        for (int it = 0; it < 16; ++it) {
            int gi = t + 256 * it;
            int j = gi >> 5, k4 = gi & 31;
            Wl[j * 32 + (k4 ^ (j & 7))] = w4[gi];
        }
#pragma unroll
        for (int it = 0; it < 4; ++it) {
            int gi = t + 256 * it;
            int m = gi >> 5, k4 = gi & 31;
            int node = base + m;
            float4 v = (node < n) ? src4[(size_t)node * 32 + k4]
                                  : make_float4(0.f, 0.f, 0.f, 0.f);
            Xl[m * 32 + k4] = v;
        }
        __syncthreads();

        const int sw = j0 & 7;
#pragma unroll 8
        for (int k4 = 0; k4 < 32; ++k4) {
            float4 w0 = Wl[j0 * 32 + (k4 ^ sw)];
            float4 w1 = Wl[j1 * 32 + (k4 ^ sw)];
#pragma unroll
            for (int i = 0; i < 8; ++i) {
                float4 xv = Xl[(w + 4 * i) * 32 + k4];
                acc0[i] += xv.x * w0.x + xv.y * w0.y + xv.z * w0.z + xv.w * w0.w;
                acc1[i] += xv.x * w1.x + xv.y * w1.y + xv.z * w1.z + xv.w * w1.w;
            }
        }
    }

    const float g0 = gamma[j0], g1 = gamma[j1];
    const float be0 = beta[j0], be1 = beta[j1];
#pragma unroll
    for (int i = 0; i < 8; ++i) {
        int node = base + w + 4 * i;
        float s  = acc0[i] + acc1[i];
        float ss = acc0[i] * acc0[i] + acc1[i] * acc1[i];
#pragma unroll
        for (int off = 32; off; off >>= 1) {
            s  += __shfl_xor(s, off);
            ss += __shfl_xor(ss, off);
        }
        float mu   = s * (1.0f / D);
        float var  = ss * (1.0f / D) - mu * mu;
        float rstd = rsqrtf(var + 1e-5f);
        if (node < n) {
            float y0 = (acc0[i] - mu) * rstd * g0 + be0;
            float y1 = (acc1[i] - mu) * rstd * g1 + be1;
            out[(size_t)node * D + j0] = fmaxf(y0, 0.f);
            out[(size_t)node * D + j1] = fmaxf(y1, 0.f);
        }
    }
}

extern "C" void kernel_launch(void* const* d_in, const int* in_sizes, int n_in,
                              void* d_out, int out_size, void* d_ws, size_t ws_size,
                              hipStream_t stream) {
    const float* x     = (const float*)d_in[0];
    const int*   ir    = (const int*)  d_in[1];
    const int*   icoln = (const int*)  d_in[2];
    const float* ival  = (const float*)d_in[3];
    const int*   orow  = (const int*)  d_in[4];
    const int*   ocol  = (const int*)  d_in[5];
    const float* oval  = (const float*)d_in[6];
    const float* Ws    = (const float*)d_in[7];
    const float* b     = (const float*)d_in[8];
    const float* Wi    = (const float*)d_in[9];
    const float* Wo    = (const float*)d_in[10];
    const float* gamma = (const float*)d_in[11];
    const float* beta  = (const float*)d_in[12];
    float* out = (float*)d_out;

    // workspace layout
    float* agg     = (float*)d_ws;                      // NT*128 floats = 51.2 MB
    int*   row_ptr = (int*)(agg + (size_t)NT * D);      // NT+1
    int*   cursor  = row_ptr + (NT + 1);                // NT
    int*   colp    = cursor + NT;                       // NE2
    float* valp    = (float*)(colp + NE2);              // NE2
    size_t need = (size_t)NT * D * 4 + (size_t)(NT + 1 + NT) * 4 + (size_t)NE2 * 8;

    float* agg_in  = agg;
    float* agg_out = agg + (size_t)N_NODES * D;

    if (ws_size >= need) {
        // CSR path: no fp32 atomics
        hipMemsetAsync(cursor, 0, (size_t)NT * sizeof(int), stream);
        hist_rows<<<(NE2 + 255) / 256, 256, 0, stream>>>(ir, orow, cursor);
        scan_counts<<<1, 1024, 0, stream>>>(cursor, row_ptr);
        scatter_edges<<<(NE2 + 255) / 256, 256, 0, stream>>>(
            ir, icoln, ival, orow, ocol, oval, cursor, colp, valp);
        gather_rows<<<NT / 4, 256, 0, stream>>>(row_ptr, colp, valp, x, agg);
    } else {
        // fallback: atomic scatter
        hipMemsetAsync(d_ws, 0, 2 * (size_t)N_NODES * D * sizeof(float), stream);
        const int eblocks = (N_EDGES * 32 + 255) / 256;
        spmm_scatter<<<eblocks, 256, 0, stream>>>(ir, icoln, ival, x, agg_in, N_EDGES);
        spmm_scatter<<<eblocks, 256, 0, stream>>>(orow, ocol, oval, x, agg_out, N_EDGES);
    }

    const int gblocks = (N_NODES + BM - 1) / BM;
    gemm_ln_relu<<<gblocks, 256, 0, stream>>>(x, agg_in, agg_out, Ws, Wi, Wo,
                                              b, gamma, beta, out, N_NODES);
}

// Round 3
// 392.321 us; speedup vs baseline: 5.5861x; 1.5326x over previous
//
#include <hip/hip_runtime.h>

#define N_NODES 50000
#define N_EDGES 600000
#define D 128
#define BM 32
#define NT (2 * N_NODES)          // 100000 combined rows (in | out)
#define NE2 (2 * N_EDGES)         // 1200000 combined edges
#define SCAN_B 1024
#define SCAN_NB ((NT + SCAN_B - 1) / SCAN_B)   // 98

// ================= CSR-build path (no fp32 atomics) =================

// Histogram of combined rows into cnt[0..NT)
__global__ __launch_bounds__(256) void hist_rows(
    const int* __restrict__ ir, const int* __restrict__ orow, int* __restrict__ cnt)
{
    int e = blockIdx.x * 256 + threadIdx.x;
    if (e < N_EDGES)      atomicAdd(&cnt[ir[e]], 1);
    else if (e < NE2)     atomicAdd(&cnt[N_NODES + orow[e - N_EDGES]], 1);
}

// Phase 1: block-local exclusive scan of cnt -> row_ptr, block sums -> bsum
__global__ __launch_bounds__(1024) void scan_partial(
    const int* __restrict__ cnt, int* __restrict__ row_ptr, int* __restrict__ bsum)
{
    __shared__ int sbuf[SCAN_B];
    const int t = threadIdx.x;
    const int i = blockIdx.x * SCAN_B + t;
    int v = (i < NT) ? cnt[i] : 0;
    sbuf[t] = v;
    __syncthreads();
    for (int off = 1; off < SCAN_B; off <<= 1) {
        int u = (t >= off) ? sbuf[t - off] : 0;
        __syncthreads();
        sbuf[t] += u;
        __syncthreads();
    }
    if (i < NT) row_ptr[i] = sbuf[t] - v;            // block-local exclusive
    if (t == SCAN_B - 1) bsum[blockIdx.x] = sbuf[t]; // block total
}

// Phase 2: exclusive scan of the 98 block sums (single tiny block)
__global__ __launch_bounds__(128) void scan_bsums(int* __restrict__ bsum)
{
    __shared__ int sbuf[128];
    const int t = threadIdx.x;
    int v = (t < SCAN_NB) ? bsum[t] : 0;
    sbuf[t] = v;
    __syncthreads();
    for (int off = 1; off < 128; off <<= 1) {
        int u = (t >= off) ? sbuf[t - off] : 0;
        __syncthreads();
        sbuf[t] += u;
        __syncthreads();
    }
    if (t < SCAN_NB) bsum[t] = sbuf[t] - v;          // exclusive block offset
}

// Phase 3: add block offsets; produce final row_ptr and cursor copy
__global__ __launch_bounds__(1024) void scan_add(
    int* __restrict__ row_ptr, const int* __restrict__ bsum, int* __restrict__ cursor)
{
    const int i = blockIdx.x * SCAN_B + threadIdx.x;
    if (i < NT) {
        int p = row_ptr[i] + bsum[blockIdx.x];
        row_ptr[i] = p;
        cursor[i] = p;
    }
    if (i == 0) row_ptr[NT] = NE2;  // total edge count is static
}

// Place each edge's (col, val) into its row bucket (packed int2: one 8B store).
__global__ __launch_bounds__(256) void scatter_edges(
    const int* __restrict__ ir, const int* __restrict__ icol, const float* __restrict__ ival,
    const int* __restrict__ orow, const int* __restrict__ ocol, const float* __restrict__ oval,
    int* __restrict__ cursor, int2* __restrict__ pairp)
{
    int e = blockIdx.x * 256 + threadIdx.x;
    int r, c; float v;
    if (e < N_EDGES)      { r = ir[e];                       c = icol[e];            v = ival[e]; }
    else if (e < NE2)     { r = N_NODES + orow[e - N_EDGES]; c = ocol[e - N_EDGES];  v = oval[e - N_EDGES]; }
    else return;
    int pos = atomicAdd(&cursor[r], 1);
    pairp[pos] = make_int2(c, __float_as_int(v));
}

// One wave per combined row: agg[r] = sum_e val[e] * x[col[e]].
__global__ __launch_bounds__(256) void gather_rows(
    const int* __restrict__ row_ptr, const int2* __restrict__ pairp,
    const float* __restrict__ x, float* __restrict__ agg)
{
    const int wv = blockIdx.x * 4 + (threadIdx.x >> 6);
    if (wv >= NT) return;
    const int lane = threadIdx.x & 63;
    const int s = row_ptr[wv];
    const int e = row_ptr[wv + 1];

    float ax = 0.f, ay = 0.f;
    const float* xb = x + lane * 2;

    int i = s;
    for (; i + 1 < e; i += 2) {   // 2-edge unroll for ILP
        int2 pa = pairp[i];
        int2 pb = pairp[i + 1];
        float va = __int_as_float(pa.y), vb = __int_as_float(pb.y);
        float2 xa = *reinterpret_cast<const float2*>(xb + (size_t)pa.x * D);
        float2 xc = *reinterpret_cast<const float2*>(xb + (size_t)pb.x * D);
        ax += va * xa.x + vb * xc.x;
        ay += va * xa.y + vb * xc.y;
    }
    if (i < e) {
        int2 pa = pairp[i];
        float v = __int_as_float(pa.y);
        float2 xa = *reinterpret_cast<const float2*>(xb + (size_t)pa.x * D);
        ax += v * xa.x;
        ay += v * xa.y;
    }
    *reinterpret_cast<float2*>(agg + (size_t)wv * D + lane * 2) = make_float2(ax, ay);
}

// ================= fallback: atomic scatter SpMM =================
__global__ __launch_bounds__(256) void spmm_scatter(
    const int* __restrict__ rows, const int* __restrict__ cols,
    const float* __restrict__ vals, const float* __restrict__ x,
    float* __restrict__ agg, int nE)
{
    int g = blockIdx.x * 256 + threadIdx.x;
    int e = g >> 5;
    if (e >= nE) return;
    int q = g & 31;
    int r = rows[e];
    int c = cols[e];
    float v = vals[e];
    float4 xv = *reinterpret_cast<const float4*>(x + (size_t)c * D + (size_t)q * 4);
    float* ap = agg + (size_t)r * D + (size_t)q * 4;
    atomicAdd(ap + 0, v * xv.x);
    atomicAdd(ap + 1, v * xv.y);
    atomicAdd(ap + 2, v * xv.z);
    atomicAdd(ap + 3, v * xv.w);
}

// ================= fused 3xGEMM + bias + LayerNorm + ReLU =================
__global__ __launch_bounds__(256) void gemm_ln_relu(
    const float* __restrict__ x, const float* __restrict__ agg_in,
    const float* __restrict__ agg_out,
    const float* __restrict__ Ws, const float* __restrict__ Wi,
    const float* __restrict__ Wo, const float* __restrict__ b,
    const float* __restrict__ gamma, const float* __restrict__ beta,
    float* __restrict__ out, int n)
{
    __shared__ float4 Wl[D * (D / 4)];   // 64 KB (swizzled)
    __shared__ float4 Xl[BM * (D / 4)];  // 16 KB

    const int t = threadIdx.x;
    const int l = t & 63;
    const int w = t >> 6;
    const int base = blockIdx.x * BM;

    const int j0 = l;
    const int j1 = l + 64;

    float acc0[8], acc1[8];
    const float bj0 = b[j0], bj1 = b[j1];
#pragma unroll
    for (int i = 0; i < 8; ++i) { acc0[i] = bj0; acc1[i] = bj1; }

    const float* srcs[3] = { x, agg_in, agg_out };
    const float* wms[3]  = { Ws, Wi, Wo };

#pragma unroll
    for (int s = 0; s < 3; ++s) {
        const float4* src4 = reinterpret_cast<const float4*>(srcs[s]);
        const float4* w4   = reinterpret_cast<const float4*>(wms[s]);
        __syncthreads();
#pragma unroll
        for (int it = 0; it < 16; ++it) {
            int gi = t + 256 * it;
            int j = gi >> 5, k4 = gi & 31;
            Wl[j * 32 + (k4 ^ (j & 7))] = w4[gi];
        }
#pragma unroll
        for (int it = 0; it < 4; ++it) {
            int gi = t + 256 * it;
            int m = gi >> 5, k4 = gi & 31;
            int node = base + m;
            float4 v = (node < n) ? src4[(size_t)node * 32 + k4]
                                  : make_float4(0.f, 0.f, 0.f, 0.f);
            Xl[m * 32 + k4] = v;
        }
        __syncthreads();

        const int sw = j0 & 7;
#pragma unroll 8
        for (int k4 = 0; k4 < 32; ++k4) {
            float4 w0 = Wl[j0 * 32 + (k4 ^ sw)];
            float4 w1 = Wl[j1 * 32 + (k4 ^ sw)];
#pragma unroll
            for (int i = 0; i < 8; ++i) {
                float4 xv = Xl[(w + 4 * i) * 32 + k4];
                acc0[i] += xv.x * w0.x + xv.y * w0.y + xv.z * w0.z + xv.w * w0.w;
                acc1[i] += xv.x * w1.x + xv.y * w1.y + xv.z * w1.z + xv.w * w1.w;
            }
        }
    }

    const float g0 = gamma[j0], g1 = gamma[j1];
    const float be0 = beta[j0], be1 = beta[j1];
#pragma unroll
    for (int i = 0; i < 8; ++i) {
        int node = base + w + 4 * i;
        float s  = acc0[i] + acc1[i];
        float ss = acc0[i] * acc0[i] + acc1[i] * acc1[i];
#pragma unroll
        for (int off = 32; off; off >>= 1) {
            s  += __shfl_xor(s, off);
            ss += __shfl_xor(ss, off);
        }
        float mu   = s * (1.0f / D);
        float var  = ss * (1.0f / D) - mu * mu;
        float rstd = rsqrtf(var + 1e-5f);
        if (node < n) {
            float y0 = (acc0[i] - mu) * rstd * g0 + be0;
            float y1 = (acc1[i] - mu) * rstd * g1 + be1;
            out[(size_t)node * D + j0] = fmaxf(y0, 0.f);
            out[(size_t)node * D + j1] = fmaxf(y1, 0.f);
        }
    }
}

extern "C" void kernel_launch(void* const* d_in, const int* in_sizes, int n_in,
                              void* d_out, int out_size, void* d_ws, size_t ws_size,
                              hipStream_t stream) {
    const float* x     = (const float*)d_in[0];
    const int*   ir    = (const int*)  d_in[1];
    const int*   icoln = (const int*)  d_in[2];
    const float* ival  = (const float*)d_in[3];
    const int*   orow  = (const int*)  d_in[4];
    const int*   ocol  = (const int*)  d_in[5];
    const float* oval  = (const float*)d_in[6];
    const float* Ws    = (const float*)d_in[7];
    const float* b     = (const float*)d_in[8];
    const float* Wi    = (const float*)d_in[9];
    const float* Wo    = (const float*)d_in[10];
    const float* gamma = (const float*)d_in[11];
    const float* beta  = (const float*)d_in[12];
    float* out = (float*)d_out;

    // workspace layout (8B-aligned pieces)
    float* agg     = (float*)d_ws;                       // NT*128 floats = 51.2 MB
    int*   row_ptr = (int*)(agg + (size_t)NT * D);       // NT+2 (pad for alignment)
    int*   cursor  = row_ptr + (NT + 2);                 // NT
    int*   bsum    = cursor + NT;                        // 128
    int2*  pairp   = (int2*)(bsum + 128);                // NE2 int2 (8B aligned)
    size_t need = (size_t)NT * D * 4 + (size_t)(NT + 2 + NT + 128) * 4 + (size_t)NE2 * 8;

    float* agg_in  = agg;
    float* agg_out = agg + (size_t)N_NODES * D;

    if (ws_size >= need) {
        // CSR path: no fp32 atomics
        hipMemsetAsync(cursor, 0, (size_t)NT * sizeof(int), stream);
        hist_rows<<<(NE2 + 255) / 256, 256, 0, stream>>>(ir, orow, cursor);
        scan_partial<<<SCAN_NB, SCAN_B, 0, stream>>>(cursor, row_ptr, bsum);
        scan_bsums<<<1, 128, 0, stream>>>(bsum);
        scan_add<<<SCAN_NB, SCAN_B, 0, stream>>>(row_ptr, bsum, cursor);
        scatter_edges<<<(NE2 + 255) / 256, 256, 0, stream>>>(
            ir, icoln, ival, orow, ocol, oval, cursor, pairp);
        gather_rows<<<NT / 4, 256, 0, stream>>>(row_ptr, pairp, x, agg);
    } else {
        // fallback: atomic scatter
        hipMemsetAsync(d_ws, 0, 2 * (size_t)N_NODES * D * sizeof(float), stream);
        const int eblocks = (N_EDGES * 32 + 255) / 256;
        spmm_scatter<<<eblocks, 256, 0, stream>>>(ir, icoln, ival, x, agg_in, N_EDGES);
        spmm_scatter<<<eblocks, 256, 0, stream>>>(orow, ocol, oval, x, agg_out, N_EDGES);
    }

    const int gblocks = (N_NODES + BM - 1) / BM;
    gemm_ln_relu<<<gblocks, 256, 0, stream>>>(x, agg_in, agg_out, Ws, Wi, Wo,
                                              b, gamma, beta, out, N_NODES);
}

// Round 4
// 280.079 us; speedup vs baseline: 7.8247x; 1.4007x over previous
//
#include <hip/hip_runtime.h>

#define N_NODES 50000
#define N_EDGES 600000
#define D 128
#define BM 32
#define NT (2 * N_NODES)          // 100000 combined rows (in | out)
#define NE2 (2 * N_EDGES)         // 1200000 combined edges
#define SCAN_B 1024
#define SCAN_NB ((NT + SCAN_B - 1) / SCAN_B)   // 98
#define NPAD 50048                // 782 * 64
#define KA 384                    // packed A columns: x | agg_in | agg_out
#define GBM 64                    // gemm M-tile

typedef __attribute__((ext_vector_type(8))) short bf16x8;
typedef __attribute__((ext_vector_type(4))) float f32x4;

__device__ inline unsigned short bfr(float x) {          // f32 -> bf16 RNE
    unsigned b = __float_as_uint(x);
    b += 0x7FFFu + ((b >> 16) & 1u);
    return (unsigned short)(b >> 16);
}
__device__ inline float bf_lo(unsigned u) { return __uint_as_float(u << 16); }
__device__ inline float bf_hi(unsigned u) { return __uint_as_float(u & 0xFFFF0000u); }

// ================= pack kernels =================

// x fp32 -> A[:, 0:128] bf16
__global__ __launch_bounds__(256) void cvt_x(const float* __restrict__ x, short* __restrict__ A)
{
    int gid = blockIdx.x * 256 + threadIdx.x;
    if (gid >= N_NODES * 32) return;
    int row = gid >> 5, c4 = gid & 31;
    float4 v = *reinterpret_cast<const float4*>(x + (size_t)row * D + c4 * 4);
    ushort4 o = { bfr(v.x), bfr(v.y), bfr(v.z), bfr(v.w) };
    *reinterpret_cast<ushort4*>(A + (size_t)row * KA + c4 * 4) = o;
}

// Wc[j][0:384] = [Ws[j] | Wi[j] | Wo[j]] bf16
__global__ __launch_bounds__(384) void cvt_w(
    const float* __restrict__ Ws, const float* __restrict__ Wi,
    const float* __restrict__ Wo, short* __restrict__ Wc)
{
    int j = blockIdx.x, k = threadIdx.x;
    float v = (k < 128) ? Ws[j * 128 + k]
            : (k < 256) ? Wi[j * 128 + k - 128]
                        : Wo[j * 128 + k - 256];
    Wc[j * KA + k] = (short)bfr(v);
}

// ================= CSR build (int atomics only) =================

__global__ __launch_bounds__(256) void hist_rows(
    const int* __restrict__ ir, const int* __restrict__ orow, int* __restrict__ cnt)
{
    int e = blockIdx.x * 256 + threadIdx.x;
    if (e < N_EDGES)      atomicAdd(&cnt[ir[e]], 1);
    else if (e < NE2)     atomicAdd(&cnt[N_NODES + orow[e - N_EDGES]], 1);
}

__global__ __launch_bounds__(1024) void scan_partial(
    const int* __restrict__ cnt, int* __restrict__ row_ptr, int* __restrict__ bsum)
{
    __shared__ int sbuf[SCAN_B];
    const int t = threadIdx.x;
    const int i = blockIdx.x * SCAN_B + t;
    int v = (i < NT) ? cnt[i] : 0;
    sbuf[t] = v;
    __syncthreads();
    for (int off = 1; off < SCAN_B; off <<= 1) {
        int u = (t >= off) ? sbuf[t - off] : 0;
        __syncthreads();
        sbuf[t] += u;
        __syncthreads();
    }
    if (i < NT) row_ptr[i] = sbuf[t] - v;
    if (t == SCAN_B - 1) bsum[blockIdx.x] = sbuf[t];
}

__global__ __launch_bounds__(128) void scan_bsums(int* __restrict__ bsum)
{
    __shared__ int sbuf[128];
    const int t = threadIdx.x;
    int v = (t < SCAN_NB) ? bsum[t] : 0;
    sbuf[t] = v;
    __syncthreads();
    for (int off = 1; off < 128; off <<= 1) {
        int u = (t >= off) ? sbuf[t - off] : 0;
        __syncthreads();
        sbuf[t] += u;
        __syncthreads();
    }
    if (t < SCAN_NB) bsum[t] = sbuf[t] - v;
}

__global__ __launch_bounds__(1024) void scan_add(
    int* __restrict__ row_ptr, const int* __restrict__ bsum, int* __restrict__ cursor)
{
    const int i = blockIdx.x * SCAN_B + threadIdx.x;
    if (i < NT) {
        int p = row_ptr[i] + bsum[blockIdx.x];
        row_ptr[i] = p;
        cursor[i] = p;
    }
    if (i == 0) row_ptr[NT] = NE2;
}

__global__ __launch_bounds__(256) void scatter_edges(
    const int* __restrict__ ir, const int* __restrict__ icol, const float* __restrict__ ival,
    const int* __restrict__ orow, const int* __restrict__ ocol, const float* __restrict__ oval,
    int* __restrict__ cursor, int2* __restrict__ pairp)
{
    int e = blockIdx.x * 256 + threadIdx.x;
    int r, c; float v;
    if (e < N_EDGES)      { r = ir[e];                       c = icol[e];            v = ival[e]; }
    else if (e < NE2)     { r = N_NODES + orow[e - N_EDGES]; c = ocol[e - N_EDGES];  v = oval[e - N_EDGES]; }
    else return;
    int pos = atomicAdd(&cursor[r], 1);
    pairp[pos] = make_int2(c, __float_as_int(v));
}

// One wave per combined row: read bf16 x-rows from A[:,0:128], accumulate fp32,
// write bf16 into A[:,128:256] (in) or A[:,256:384] (out).
__global__ __launch_bounds__(256) void gather_rows(
    const int* __restrict__ row_ptr, const int2* __restrict__ pairp,
    short* __restrict__ A)
{
    const int wv = blockIdx.x * 4 + (threadIdx.x >> 6);
    if (wv >= NT) return;
    const int lane = threadIdx.x & 63;
    const int s = row_ptr[wv], e = row_ptr[wv + 1];

    float ax = 0.f, ay = 0.f;
    char* Ab = (char*)A;
    const size_t loff = (size_t)lane * 4;

    int i = s;
    for (; i + 1 < e; i += 2) {
        int2 pa = pairp[i], pb = pairp[i + 1];
        float va = __int_as_float(pa.y), vb = __int_as_float(pb.y);
        unsigned ua = *(const unsigned*)(Ab + (size_t)pa.x * (KA * 2) + loff);
        unsigned ub = *(const unsigned*)(Ab + (size_t)pb.x * (KA * 2) + loff);
        ax += va * bf_lo(ua) + vb * bf_lo(ub);
        ay += va * bf_hi(ua) + vb * bf_hi(ub);
    }
    if (i < e) {
        int2 pa = pairp[i];
        float v = __int_as_float(pa.y);
        unsigned ua = *(const unsigned*)(Ab + (size_t)pa.x * (KA * 2) + loff);
        ax += v * bf_lo(ua);
        ay += v * bf_hi(ua);
    }
    unsigned o = ((unsigned)bfr(ay) << 16) | (unsigned)bfr(ax);
    size_t dst = (wv < N_NODES)
               ? ((size_t)wv * (KA * 2) + 256 + loff)
               : ((size_t)(wv - N_NODES) * (KA * 2) + 512 + loff);
    *(unsigned*)(Ab + dst) = o;
}

// ================= MFMA GEMM + bias + LayerNorm + ReLU =================
// 512 threads = 8 waves; wave w owns output cols [w*16, w*16+16).
// B-fragments (12 k-steps) held in registers; A tile (64 x 384 bf16) in LDS,
// XOR-swizzled per 16B slot: slot (row, c16) stored at c16 ^ (row & 7).
__global__ __launch_bounds__(512) void gemm_mfma(
    const short* __restrict__ A, const short* __restrict__ Wc,
    const float* __restrict__ b, const float* __restrict__ gamma,
    const float* __restrict__ beta, float* __restrict__ out)
{
    __shared__ short Alds[GBM * KA];     // 48 KB
    __shared__ float red[8][64][2];      // 4 KB
    __shared__ float2 mustd[64];         // 0.5 KB

    const int t = threadIdx.x;
    const int l = t & 63, w = t >> 6;
    const int q = l >> 4, c = l & 15;
    const int base = blockIdx.x * GBM;

    // B-fragments: n-row = w*16 + c, k-chunk = s*32 + q*8
    bf16x8 bfrag[12];
    const short* wrow = Wc + (size_t)(w * 16 + c) * KA + q * 8;
#pragma unroll
    for (int s = 0; s < 12; ++s)
        bfrag[s] = *reinterpret_cast<const bf16x8*>(wrow + s * 32);

    // Stage A tile: 3072 x 16B slots. Global read linear (coalesced),
    // LDS write swizzled.
#pragma unroll
    for (int i = 0; i < 6; ++i) {
        int slot = t + i * 512;
        int row = slot / 48, c16 = slot % 48;
        bf16x8 v = *reinterpret_cast<const bf16x8*>(A + (size_t)(base + row) * KA + c16 * 8);
        *reinterpret_cast<bf16x8*>(&Alds[row * KA + (c16 ^ (row & 7)) * 8]) = v;
    }
    __syncthreads();

    f32x4 acc[4];
#pragma unroll
    for (int rg = 0; rg < 4; ++rg) acc[rg] = (f32x4){0.f, 0.f, 0.f, 0.f};

#pragma unroll
    for (int s = 0; s < 12; ++s) {
#pragma unroll
        for (int rg = 0; rg < 4; ++rg) {
            int row = rg * 16 + c;
            int c16 = (s * 4 + q) ^ (row & 7);
            bf16x8 af = *reinterpret_cast<const bf16x8*>(&Alds[row * KA + c16 * 8]);
            acc[rg] = __builtin_amdgcn_mfma_f32_16x16x32_bf16(af, bfrag[s], acc[rg], 0, 0, 0);
        }
    }

    // ---- bias + LN partials (16-lane groups share a row's 16 cols of this wave) ----
    const float bj = b[w * 16 + c];
    const float gj = gamma[w * 16 + c];
    const float ej = beta[w * 16 + c];

#pragma unroll
    for (int rg = 0; rg < 4; ++rg) {
#pragma unroll
        for (int r = 0; r < 4; ++r) {
            float hv = acc[rg][r] + bj;
            acc[rg][r] = hv;
            float s1 = hv, s2 = hv * hv;
#pragma unroll
            for (int m = 1; m < 16; m <<= 1) {
                s1 += __shfl_xor(s1, m);
                s2 += __shfl_xor(s2, m);
            }
            if (c == 0) {
                int row = rg * 16 + q * 4 + r;
                red[w][row][0] = s1;
                red[w][row][1] = s2;
            }
        }
    }
    __syncthreads();

    if (t < 64) {
        float s1 = 0.f, s2 = 0.f;
#pragma unroll
        for (int ww = 0; ww < 8; ++ww) { s1 += red[ww][t][0]; s2 += red[ww][t][1]; }
        float mu = s1 * (1.f / 128.f);
        float var = s2 * (1.f / 128.f) - mu * mu;
        mustd[t] = make_float2(mu, rsqrtf(var + 1e-5f));
    }
    __syncthreads();

#pragma unroll
    for (int rg = 0; rg < 4; ++rg) {
        int row0 = rg * 16 + q * 4;
        int node0 = base + row0;
#pragma unroll
        for (int r = 0; r < 4; ++r) {
            float2 ms = mustd[row0 + r];
            float y = (acc[rg][r] - ms.x) * ms.y * gj + ej;
            y = fmaxf(y, 0.f);
            if (node0 + r < N_NODES)
                out[(size_t)(node0 + r) * D + w * 16 + c] = y;
        }
    }
}

// ================= fp32 fallback (small ws) =================
__global__ __launch_bounds__(256) void spmm_scatter(
    const int* __restrict__ rows, const int* __restrict__ cols,
    const float* __restrict__ vals, const float* __restrict__ x,
    float* __restrict__ agg, int nE)
{
    int g = blockIdx.x * 256 + threadIdx.x;
    int e = g >> 5;
    if (e >= nE) return;
    int q = g & 31;
    int r = rows[e];
    int c = cols[e];
    float v = vals[e];
    float4 xv = *reinterpret_cast<const float4*>(x + (size_t)c * D + (size_t)q * 4);
    float* ap = agg + (size_t)r * D + (size_t)q * 4;
    atomicAdd(ap + 0, v * xv.x);
    atomicAdd(ap + 1, v * xv.y);
    atomicAdd(ap + 2, v * xv.z);
    atomicAdd(ap + 3, v * xv.w);
}

__global__ __launch_bounds__(256) void gemm_ln_relu(
    const float* __restrict__ x, const float* __restrict__ agg_in,
    const float* __restrict__ agg_out,
    const float* __restrict__ Ws, const float* __restrict__ Wi,
    const float* __restrict__ Wo, const float* __restrict__ b,
    const float* __restrict__ gamma, const float* __restrict__ beta,
    float* __restrict__ out, int n)
{
    __shared__ float4 Wl[D * (D / 4)];
    __shared__ float4 Xl[BM * (D / 4)];

    const int t = threadIdx.x;
    const int l = t & 63;
    const int w = t >> 6;
    const int base = blockIdx.x * BM;
    const int j0 = l, j1 = l + 64;

    float acc0[8], acc1[8];
    const float bj0 = b[j0], bj1 = b[j1];
#pragma unroll
    for (int i = 0; i < 8; ++i) { acc0[i] = bj0; acc1[i] = bj1; }

    const float* srcs[3] = { x, agg_in, agg_out };
    const float* wms[3]  = { Ws, Wi, Wo };

#pragma unroll
    for (int s = 0; s < 3; ++s) {
        const float4* src4 = reinterpret_cast<const float4*>(srcs[s]);
        const float4* w4   = reinterpret_cast<const float4*>(wms[s]);
        __syncthreads();
#pragma unroll
        for (int it = 0; it < 16; ++it) {
            int gi = t + 256 * it;
            int j = gi >> 5, k4 = gi & 31;
            Wl[j * 32 + (k4 ^ (j & 7))] = w4[gi];
        }
#pragma unroll
        for (int it = 0; it < 4; ++it) {
            int gi = t + 256 * it;
            int m = gi >> 5, k4 = gi & 31;
            int node = base + m;
            float4 v = (node < n) ? src4[(size_t)node * 32 + k4]
                                  : make_float4(0.f, 0.f, 0.f, 0.f);
            Xl[m * 32 + k4] = v;
        }
        __syncthreads();

        const int sw = j0 & 7;
#pragma unroll 8
        for (int k4 = 0; k4 < 32; ++k4) {
            float4 w0 = Wl[j0 * 32 + (k4 ^ sw)];
            float4 w1 = Wl[j1 * 32 + (k4 ^ sw)];
#pragma unroll
            for (int i = 0; i < 8; ++i) {
                float4 xv = Xl[(w + 4 * i) * 32 + k4];
                acc0[i] += xv.x * w0.x + xv.y * w0.y + xv.z * w0.z + xv.w * w0.w;
                acc1[i] += xv.x * w1.x + xv.y * w1.y + xv.z * w1.z + xv.w * w1.w;
            }
        }
    }

    const float g0 = gamma[j0], g1 = gamma[j1];
    const float be0 = beta[j0], be1 = beta[j1];
#pragma unroll
    for (int i = 0; i < 8; ++i) {
        int node = base + w + 4 * i;
        float s  = acc0[i] + acc1[i];
        float ss = acc0[i] * acc0[i] + acc1[i] * acc1[i];
#pragma unroll
        for (int off = 32; off; off >>= 1) {
            s  += __shfl_xor(s, off);
            ss += __shfl_xor(ss, off);
        }
        float mu   = s * (1.0f / D);
        float var  = ss * (1.0f / D) - mu * mu;
        float rstd = rsqrtf(var + 1e-5f);
        if (node < n) {
            float y0 = (acc0[i] - mu) * rstd * g0 + be0;
            float y1 = (acc1[i] - mu) * rstd * g1 + be1;
            out[(size_t)node * D + j0] = fmaxf(y0, 0.f);
            out[(size_t)node * D + j1] = fmaxf(y1, 0.f);
        }
    }
}

extern "C" void kernel_launch(void* const* d_in, const int* in_sizes, int n_in,
                              void* d_out, int out_size, void* d_ws, size_t ws_size,
                              hipStream_t stream) {
    const float* x     = (const float*)d_in[0];
    const int*   ir    = (const int*)  d_in[1];
    const int*   icoln = (const int*)  d_in[2];
    const float* ival  = (const float*)d_in[3];
    const int*   orow  = (const int*)  d_in[4];
    const int*   ocol  = (const int*)  d_in[5];
    const float* oval  = (const float*)d_in[6];
    const float* Ws    = (const float*)d_in[7];
    const float* b     = (const float*)d_in[8];
    const float* Wi    = (const float*)d_in[9];
    const float* Wo    = (const float*)d_in[10];
    const float* gamma = (const float*)d_in[11];
    const float* beta  = (const float*)d_in[12];
    float* out = (float*)d_out;

    // workspace layout
    short* A       = (short*)d_ws;                         // NPAD x 384 bf16 = 38.44 MB
    short* Wc      = A + (size_t)NPAD * KA;                // 128 x 384 bf16 = 96 KB
    int*   row_ptr = (int*)(Wc + (size_t)128 * KA);        // NT+2
    int*   cursor  = row_ptr + (NT + 2);                   // NT
    int*   bsum    = cursor + NT;                          // 128
    int2*  pairp   = (int2*)(bsum + 128);                  // NE2
    size_t need = (size_t)NPAD * KA * 2 + (size_t)128 * KA * 2
                + (size_t)(NT + 2 + NT + 128) * 4 + (size_t)NE2 * 8;

    if (ws_size >= need) {
        // zero cursor + A pad rows
        hipMemsetAsync(cursor, 0, (size_t)NT * sizeof(int), stream);
        hipMemsetAsync(A + (size_t)N_NODES * KA, 0,
                       (size_t)(NPAD - N_NODES) * KA * 2, stream);

        cvt_x<<<(N_NODES * 32 + 255) / 256, 256, 0, stream>>>(x, A);
        cvt_w<<<128, 384, 0, stream>>>(Ws, Wi, Wo, Wc);

        hist_rows<<<(NE2 + 255) / 256, 256, 0, stream>>>(ir, orow, cursor);
        scan_partial<<<SCAN_NB, SCAN_B, 0, stream>>>(cursor, row_ptr, bsum);
        scan_bsums<<<1, 128, 0, stream>>>(bsum);
        scan_add<<<SCAN_NB, SCAN_B, 0, stream>>>(row_ptr, bsum, cursor);
        scatter_edges<<<(NE2 + 255) / 256, 256, 0, stream>>>(
            ir, icoln, ival, orow, ocol, oval, cursor, pairp);
        gather_rows<<<NT / 4, 256, 0, stream>>>(row_ptr, pairp, A);

        gemm_mfma<<<NPAD / GBM, 512, 0, stream>>>(A, Wc, b, gamma, beta, out);
    } else {
        // fp32 fallback
        float* agg_in  = (float*)d_ws;
        float* agg_out = agg_in + (size_t)N_NODES * D;
        hipMemsetAsync(d_ws, 0, 2 * (size_t)N_NODES * D * sizeof(float), stream);
        const int eblocks = (N_EDGES * 32 + 255) / 256;
        spmm_scatter<<<eblocks, 256, 0, stream>>>(ir, icoln, ival, x, agg_in, N_EDGES);
        spmm_scatter<<<eblocks, 256, 0, stream>>>(orow, ocol, oval, x, agg_out, N_EDGES);
        const int gblocks = (N_NODES + BM - 1) / BM;
        gemm_ln_relu<<<gblocks, 256, 0, stream>>>(x, agg_in, agg_out, Ws, Wi, Wo,
                                                  b, gamma, beta, out, N_NODES);
    }
}

// Round 5
// 175.059 us; speedup vs baseline: 12.5188x; 1.5999x over previous
//
#include <hip/hip_runtime.h>

#define N_NODES 50000
#define N_EDGES 600000
#define D 128
#define BM 32
#define NT (2 * N_NODES)          // 100000 combined rows (in | out)
#define NE2 (2 * N_EDGES)         // 1200000 combined edges
#define NPAD 50048                // 782 * 64
#define KA 384                    // packed A columns: x | agg_in | agg_out
#define GBM 64                    // gemm M-tile
#define NB 391                    // buckets of 256 combined rows (100000 >> 8 -> 390)
#define BROWS 256
#define CAPE 4096                 // pass-B per-batch LDS edge capacity
#define CHUNK_A 8192              // pass-A edges per block

typedef __attribute__((ext_vector_type(8))) short bf16x8;
typedef __attribute__((ext_vector_type(4))) float f32x4;

__device__ inline unsigned short bfr(float x) {          // f32 -> bf16 RNE
    unsigned b = __float_as_uint(x);
    b += 0x7FFFu + ((b >> 16) & 1u);
    return (unsigned short)(b >> 16);
}
__device__ inline float bf_lo(unsigned u) { return __uint_as_float(u << 16); }
__device__ inline float bf_hi(unsigned u) { return __uint_as_float(u & 0xFFFF0000u); }

// ================= pack kernels =================

__global__ __launch_bounds__(256) void cvt_x(const float* __restrict__ x, short* __restrict__ A)
{
    int gid = blockIdx.x * 256 + threadIdx.x;
    if (gid >= N_NODES * 32) return;
    int row = gid >> 5, c4 = gid & 31;
    float4 v = *reinterpret_cast<const float4*>(x + (size_t)row * D + c4 * 4);
    ushort4 o = { bfr(v.x), bfr(v.y), bfr(v.z), bfr(v.w) };
    *reinterpret_cast<ushort4*>(A + (size_t)row * KA + c4 * 4) = o;
}

__global__ __launch_bounds__(384) void cvt_w(
    const float* __restrict__ Ws, const float* __restrict__ Wi,
    const float* __restrict__ Wo, short* __restrict__ Wc)
{
    int j = blockIdx.x, k = threadIdx.x;
    float v = (k < 128) ? Ws[j * 128 + k]
            : (k < 256) ? Wi[j * 128 + k - 128]
                        : Wo[j * 128 + k - 256];
    Wc[j * KA + k] = (short)bfr(v);
}

// ================= bucket CSR build =================

// Count edges per 256-row bucket (LDS pre-aggregation).
__global__ __launch_bounds__(1024) void bucket_hist(
    const int* __restrict__ ir, const int* __restrict__ orow, int* __restrict__ bcnt)
{
    __shared__ int h[NB];
    for (int i = threadIdx.x; i < NB; i += 1024) h[i] = 0;
    __syncthreads();
    int stride = gridDim.x * 1024;
    for (int e = blockIdx.x * 1024 + threadIdx.x; e < NE2; e += stride) {
        int r = (e < N_EDGES) ? ir[e] : N_NODES + orow[e - N_EDGES];
        atomicAdd(&h[r >> 8], 1);
    }
    __syncthreads();
    for (int i = threadIdx.x; i < NB; i += 1024)
        if (h[i]) atomicAdd(&bcnt[i], h[i]);
}

// Exclusive scan of 391 bucket counts -> bbase, cursor copy -> bcur.
__global__ __launch_bounds__(512) void scan_buckets(
    const int* __restrict__ bcnt, int* __restrict__ bbase, int* __restrict__ bcur)
{
    __shared__ int s[512];
    const int t = threadIdx.x;
    int v = (t < NB) ? bcnt[t] : 0;
    s[t] = v;
    __syncthreads();
    for (int o = 1; o < 512; o <<= 1) {
        int u = (t >= o) ? s[t - o] : 0;
        __syncthreads();
        s[t] += u;
        __syncthreads();
    }
    if (t < NB) { bbase[t] = s[t] - v; bcur[t] = s[t] - v; }
}

// Pass A: bucket-sort edges with block-level reservations (write-local).
// pairp[pos] = { col | (row&255)<<16 , val }
__global__ __launch_bounds__(1024) void scatter_buckets(
    const int* __restrict__ ir, const int* __restrict__ icol, const float* __restrict__ ival,
    const int* __restrict__ orow, const int* __restrict__ ocol, const float* __restrict__ oval,
    int* __restrict__ bcur, int2* __restrict__ pairp)
{
    __shared__ int hist[NB];
    __shared__ int cur[NB];
    const int t = threadIdx.x;
    for (int i = t; i < NB; i += 1024) hist[i] = 0;
    __syncthreads();

    const int e0 = blockIdx.x * CHUNK_A;
    int rr[8], cc[8]; float vv[8];
#pragma unroll
    for (int i = 0; i < 8; ++i) {
        int e = e0 + t + i * 1024;
        if (e < N_EDGES)      { rr[i] = ir[e];                       cc[i] = icol[e];           vv[i] = ival[e]; }
        else if (e < NE2)     { rr[i] = N_NODES + orow[e - N_EDGES]; cc[i] = ocol[e - N_EDGES]; vv[i] = oval[e - N_EDGES]; }
        else                  { rr[i] = -1; cc[i] = 0; vv[i] = 0.f; }
        if (rr[i] >= 0) atomicAdd(&hist[rr[i] >> 8], 1);
    }
    __syncthreads();
    for (int i = t; i < NB; i += 1024) {
        int c = hist[i];
        cur[i] = c ? atomicAdd(&bcur[i], c) : 0;
    }
    __syncthreads();
#pragma unroll
    for (int i = 0; i < 8; ++i) {
        if (rr[i] < 0) continue;
        int pos = atomicAdd(&cur[rr[i] >> 8], 1);
        pairp[pos] = make_int2((cc[i] & 0xFFFF) | ((rr[i] & 255) << 16), __float_as_int(vv[i]));
    }
}

// Pass B (fused row-sort + gather): one block per bucket.
// 16 waves x 16 rows; counting-sort bucket edges by local row in LDS, then
// per-row register-accumulated gather of bf16 x rows; bf16 write into A.
__global__ __launch_bounds__(1024) void bucket_spmm(
    const int* __restrict__ bbase, const int* __restrict__ bcnt,
    const int2* __restrict__ pairp, short* __restrict__ A)
{
    __shared__ int2 eraw[CAPE];      // 32 KB
    __shared__ int2 ed[CAPE];        // 32 KB sorted
    __shared__ int  rs[BROWS];       // scan buffer
    __shared__ int  rstart[BROWS + 1];
    __shared__ int  rcur[BROWS];

    const int t = threadIdx.x;
    const int b = blockIdx.x;
    const int base = bbase[b];
    const int n = bcnt[b];
    const int w = t >> 6, lane = t & 63;
    const int row0 = w * 16;
    const char* Ab = (const char*)A;

    float ax[16], ay[16];
#pragma unroll
    for (int i = 0; i < 16; ++i) { ax[i] = 0.f; ay[i] = 0.f; }

    for (int s0 = 0; s0 < n; s0 += CAPE) {
        const int m = min(n - s0, CAPE);
        for (int i = t; i < BROWS; i += 1024) rs[i] = 0;
        __syncthreads();
        // load + count
        for (int i = t; i < m; i += 1024) {
            int2 p = pairp[base + s0 + i];
            eraw[i] = p;
            atomicAdd(&rs[(p.x >> 16) & 255], 1);
        }
        __syncthreads();
        // scan 256 counters (inclusive -> exclusive starts)
        int v = (t < BROWS) ? rs[t] : 0;
        int acc = v;
        for (int o = 1; o < BROWS; o <<= 1) {
            int u = (t >= o && t < BROWS) ? rs[t - o] : 0;
            __syncthreads();
            if (t < BROWS) { acc += u; rs[t] = acc; }
            __syncthreads();
        }
        if (t < BROWS) { rstart[t] = acc - v; rcur[t] = acc - v; }
        if (t == BROWS - 1) rstart[BROWS] = acc;
        __syncthreads();
        // place
        for (int i = t; i < m; i += 1024) {
            int2 p = eraw[i];
            int pos = atomicAdd(&rcur[(p.x >> 16) & 255], 1);
            ed[pos] = p;
        }
        __syncthreads();
        // gather: wave w owns rows row0..row0+15
#pragma unroll
        for (int ri = 0; ri < 16; ++ri) {
            const int r = row0 + ri;
            int i = rstart[r];
            const int e2 = rstart[r + 1];
            float lax = ax[ri], lay = ay[ri];
            for (; i + 1 < e2; i += 2) {
                int2 pa = ed[i], pb = ed[i + 1];
                float va = __int_as_float(pa.y), vb = __int_as_float(pb.y);
                unsigned ua = *(const unsigned*)(Ab + (size_t)(pa.x & 0xFFFF) * (KA * 2) + lane * 4);
                unsigned ub = *(const unsigned*)(Ab + (size_t)(pb.x & 0xFFFF) * (KA * 2) + lane * 4);
                lax += va * bf_lo(ua) + vb * bf_lo(ub);
                lay += va * bf_hi(ua) + vb * bf_hi(ub);
            }
            if (i < e2) {
                int2 pa = ed[i];
                float va = __int_as_float(pa.y);
                unsigned ua = *(const unsigned*)(Ab + (size_t)(pa.x & 0xFFFF) * (KA * 2) + lane * 4);
                lax += va * bf_lo(ua);
                lay += va * bf_hi(ua);
            }
            ax[ri] = lax; ay[ri] = lay;
        }
        __syncthreads();   // before next batch reuses ed/eraw
    }

    // write agg rows (bf16) into A columns [128:256) (in) / [256:384) (out)
    char* Aw = (char*)A;
#pragma unroll
    for (int ri = 0; ri < 16; ++ri) {
        int wv = b * BROWS + row0 + ri;
        if (wv >= NT) continue;
        unsigned o = ((unsigned)bfr(ay[ri]) << 16) | (unsigned)bfr(ax[ri]);
        size_t dst = (wv < N_NODES)
                   ? ((size_t)wv * (KA * 2) + 256 + lane * 4)
                   : ((size_t)(wv - N_NODES) * (KA * 2) + 512 + lane * 4);
        *(unsigned*)(Aw + dst) = o;
    }
}

// ================= MFMA GEMM + bias + LayerNorm + ReLU =================
__global__ __launch_bounds__(512) void gemm_mfma(
    const short* __restrict__ A, const short* __restrict__ Wc,
    const float* __restrict__ b, const float* __restrict__ gamma,
    const float* __restrict__ beta, float* __restrict__ out)
{
    __shared__ short Alds[GBM * KA];     // 48 KB
    __shared__ float red[8][64][2];      // 4 KB
    __shared__ float2 mustd[64];

    const int t = threadIdx.x;
    const int l = t & 63, w = t >> 6;
    const int q = l >> 4, c = l & 15;
    const int base = blockIdx.x * GBM;

    bf16x8 bfrag[12];
    const short* wrow = Wc + (size_t)(w * 16 + c) * KA + q * 8;
#pragma unroll
    for (int s = 0; s < 12; ++s)
        bfrag[s] = *reinterpret_cast<const bf16x8*>(wrow + s * 32);

#pragma unroll
    for (int i = 0; i < 6; ++i) {
        int slot = t + i * 512;
        int row = slot / 48, c16 = slot % 48;
        bf16x8 v = *reinterpret_cast<const bf16x8*>(A + (size_t)(base + row) * KA + c16 * 8);
        *reinterpret_cast<bf16x8*>(&Alds[row * KA + (c16 ^ (row & 7)) * 8]) = v;
    }
    __syncthreads();

    f32x4 acc[4];
#pragma unroll
    for (int rg = 0; rg < 4; ++rg) acc[rg] = (f32x4){0.f, 0.f, 0.f, 0.f};

#pragma unroll
    for (int s = 0; s < 12; ++s) {
#pragma unroll
        for (int rg = 0; rg < 4; ++rg) {
            int row = rg * 16 + c;
            int c16 = (s * 4 + q) ^ (row & 7);
            bf16x8 af = *reinterpret_cast<const bf16x8*>(&Alds[row * KA + c16 * 8]);
            acc[rg] = __builtin_amdgcn_mfma_f32_16x16x32_bf16(af, bfrag[s], acc[rg], 0, 0, 0);
        }
    }

    const float bj = b[w * 16 + c];
    const float gj = gamma[w * 16 + c];
    const float ej = beta[w * 16 + c];

#pragma unroll
    for (int rg = 0; rg < 4; ++rg) {
#pragma unroll
        for (int r = 0; r < 4; ++r) {
            float hv = acc[rg][r] + bj;
            acc[rg][r] = hv;
            float s1 = hv, s2 = hv * hv;
#pragma unroll
            for (int m = 1; m < 16; m <<= 1) {
                s1 += __shfl_xor(s1, m);
                s2 += __shfl_xor(s2, m);
            }
            if (c == 0) {
                int row = rg * 16 + q * 4 + r;
                red[w][row][0] = s1;
                red[w][row][1] = s2;
            }
        }
    }
    __syncthreads();

    if (t < 64) {
        float s1 = 0.f, s2 = 0.f;
#pragma unroll
        for (int ww = 0; ww < 8; ++ww) { s1 += red[ww][t][0]; s2 += red[ww][t][1]; }
        float mu = s1 * (1.f / 128.f);
        float var = s2 * (1.f / 128.f) - mu * mu;
        mustd[t] = make_float2(mu, rsqrtf(var + 1e-5f));
    }
    __syncthreads();

#pragma unroll
    for (int rg = 0; rg < 4; ++rg) {
        int row0 = rg * 16 + q * 4;
        int node0 = base + row0;
#pragma unroll
        for (int r = 0; r < 4; ++r) {
            float2 ms = mustd[row0 + r];
            float y = (acc[rg][r] - ms.x) * ms.y * gj + ej;
            y = fmaxf(y, 0.f);
            if (node0 + r < N_NODES)
                out[(size_t)(node0 + r) * D + w * 16 + c] = y;
        }
    }
}

// ================= fp32 fallback (small ws) =================
__global__ __launch_bounds__(256) void spmm_scatter(
    const int* __restrict__ rows, const int* __restrict__ cols,
    const float* __restrict__ vals, const float* __restrict__ x,
    float* __restrict__ agg, int nE)
{
    int g = blockIdx.x * 256 + threadIdx.x;
    int e = g >> 5;
    if (e >= nE) return;
    int q = g & 31;
    int r = rows[e], c = cols[e];
    float v = vals[e];
    float4 xv = *reinterpret_cast<const float4*>(x + (size_t)c * D + (size_t)q * 4);
    float* ap = agg + (size_t)r * D + (size_t)q * 4;
    atomicAdd(ap + 0, v * xv.x);
    atomicAdd(ap + 1, v * xv.y);
    atomicAdd(ap + 2, v * xv.z);
    atomicAdd(ap + 3, v * xv.w);
}

__global__ __launch_bounds__(256) void gemm_ln_relu(
    const float* __restrict__ x, const float* __restrict__ agg_in,
    const float* __restrict__ agg_out,
    const float* __restrict__ Ws, const float* __restrict__ Wi,
    const float* __restrict__ Wo, const float* __restrict__ b,
    const float* __restrict__ gamma, const float* __restrict__ beta,
    float* __restrict__ out, int n)
{
    __shared__ float4 Wl[D * (D / 4)];
    __shared__ float4 Xl[BM * (D / 4)];

    const int t = threadIdx.x;
    const int l = t & 63;
    const int w = t >> 6;
    const int base = blockIdx.x * BM;
    const int j0 = l, j1 = l + 64;

    float acc0[8], acc1[8];
    const float bj0 = b[j0], bj1 = b[j1];
#pragma unroll
    for (int i = 0; i < 8; ++i) { acc0[i] = bj0; acc1[i] = bj1; }

    const float* srcs[3] = { x, agg_in, agg_out };
    const float* wms[3]  = { Ws, Wi, Wo };

#pragma unroll
    for (int s = 0; s < 3; ++s) {
        const float4* src4 = reinterpret_cast<const float4*>(srcs[s]);
        const float4* w4   = reinterpret_cast<const float4*>(wms[s]);
        __syncthreads();
#pragma unroll
        for (int it = 0; it < 16; ++it) {
            int gi = t + 256 * it;
            int j = gi >> 5, k4 = gi & 31;
            Wl[j * 32 + (k4 ^ (j & 7))] = w4[gi];
        }
#pragma unroll
        for (int it = 0; it < 4; ++it) {
            int gi = t + 256 * it;
            int m = gi >> 5, k4 = gi & 31;
            int node = base + m;
            float4 v = (node < n) ? src4[(size_t)node * 32 + k4]
                                  : make_float4(0.f, 0.f, 0.f, 0.f);
            Xl[m * 32 + k4] = v;
        }
        __syncthreads();

        const int sw = j0 & 7;
#pragma unroll 8
        for (int k4 = 0; k4 < 32; ++k4) {
            float4 w0 = Wl[j0 * 32 + (k4 ^ sw)];
            float4 w1 = Wl[j1 * 32 + (k4 ^ sw)];
#pragma unroll
            for (int i = 0; i < 8; ++i) {
                float4 xv = Xl[(w + 4 * i) * 32 + k4];
                acc0[i] += xv.x * w0.x + xv.y * w0.y + xv.z * w0.z + xv.w * w0.w;
                acc1[i] += xv.x * w1.x + xv.y * w1.y + xv.z * w1.z + xv.w * w1.w;
            }
        }
    }

    const float g0 = gamma[j0], g1 = gamma[j1];
    const float be0 = beta[j0], be1 = beta[j1];
#pragma unroll
    for (int i = 0; i < 8; ++i) {
        int node = base + w + 4 * i;
        float s  = acc0[i] + acc1[i];
        float ss = acc0[i] * acc0[i] + acc1[i] * acc1[i];
#pragma unroll
        for (int off = 32; off; off >>= 1) {
            s  += __shfl_xor(s, off);
            ss += __shfl_xor(ss, off);
        }
        float mu   = s * (1.0f / D);
        float var  = ss * (1.0f / D) - mu * mu;
        float rstd = rsqrtf(var + 1e-5f);
        if (node < n) {
            float y0 = (acc0[i] - mu) * rstd * g0 + be0;
            float y1 = (acc1[i] - mu) * rstd * g1 + be1;
            out[(size_t)node * D + j0] = fmaxf(y0, 0.f);
            out[(size_t)node * D + j1] = fmaxf(y1, 0.f);
        }
    }
}

extern "C" void kernel_launch(void* const* d_in, const int* in_sizes, int n_in,
                              void* d_out, int out_size, void* d_ws, size_t ws_size,
                              hipStream_t stream) {
    const float* x     = (const float*)d_in[0];
    const int*   ir    = (const int*)  d_in[1];
    const int*   icoln = (const int*)  d_in[2];
    const float* ival  = (const float*)d_in[3];
    const int*   orow  = (const int*)  d_in[4];
    const int*   ocol  = (const int*)  d_in[5];
    const float* oval  = (const float*)d_in[6];
    const float* Ws    = (const float*)d_in[7];
    const float* b     = (const float*)d_in[8];
    const float* Wi    = (const float*)d_in[9];
    const float* Wo    = (const float*)d_in[10];
    const float* gamma = (const float*)d_in[11];
    const float* beta  = (const float*)d_in[12];
    float* out = (float*)d_out;

    // workspace layout
    short* A     = (short*)d_ws;                     // NPAD x 384 bf16 = 38.44 MB
    short* Wc    = A + (size_t)NPAD * KA;            // 128 x 384 bf16
    int*   bcnt  = (int*)(Wc + (size_t)128 * KA);    // NB
    int*   bbase = bcnt + NB;                        // NB
    int*   bcur  = bbase + NB;                       // NB + pad to even
    int2*  pairp = (int2*)(bcur + NB + (NB * 3) % 2 + 1); // NE2 int2, 8B aligned
    size_t need  = (size_t)NPAD * KA * 2 + (size_t)128 * KA * 2
                 + (size_t)(3 * NB + 2) * 4 + (size_t)NE2 * 8;

    if (ws_size >= need) {
        hipMemsetAsync(bcnt, 0, NB * sizeof(int), stream);
        hipMemsetAsync(A + (size_t)N_NODES * KA, 0,
                       (size_t)(NPAD - N_NODES) * KA * 2, stream);

        cvt_x<<<(N_NODES * 32 + 255) / 256, 256, 0, stream>>>(x, A);
        cvt_w<<<128, 384, 0, stream>>>(Ws, Wi, Wo, Wc);

        bucket_hist<<<128, 1024, 0, stream>>>(ir, orow, bcnt);
        scan_buckets<<<1, 512, 0, stream>>>(bcnt, bbase, bcur);
        scatter_buckets<<<(NE2 + CHUNK_A - 1) / CHUNK_A, 1024, 0, stream>>>(
            ir, icoln, ival, orow, ocol, oval, bcur, pairp);
        bucket_spmm<<<NB, 1024, 0, stream>>>(bbase, bcnt, pairp, A);

        gemm_mfma<<<NPAD / GBM, 512, 0, stream>>>(A, Wc, b, gamma, beta, out);
    } else {
        float* agg_in  = (float*)d_ws;
        float* agg_out = agg_in + (size_t)N_NODES * D;
        hipMemsetAsync(d_ws, 0, 2 * (size_t)N_NODES * D * sizeof(float), stream);
        const int eblocks = (N_EDGES * 32 + 255) / 256;
        spmm_scatter<<<eblocks, 256, 0, stream>>>(ir, icoln, ival, x, agg_in, N_EDGES);
        spmm_scatter<<<eblocks, 256, 0, stream>>>(orow, ocol, oval, x, agg_out, N_EDGES);
        const int gblocks = (N_NODES + BM - 1) / BM;
        gemm_ln_relu<<<gblocks, 256, 0, stream>>>(x, agg_in, agg_out, Ws, Wi, Wo,
                                                  b, gamma, beta, out, N_NODES);
    }
}

// Round 6
// 145.515 us; speedup vs baseline: 15.0606x; 1.2030x over previous
//
#include <hip/hip_runtime.h>

#define N_NODES 50000
#define N_EDGES 600000
#define D 128
#define BM 32
#define NT (2 * N_NODES)          // 100000 combined rows (in | out)
#define NE2 (2 * N_EDGES)         // 1200000 combined edges
#define NPAD 50048                // 782 * 64
#define KA 384                    // packed A columns: x | agg_in | agg_out
#define GBM 64                    // gemm M-tile
#define NB 1563                   // buckets of 64 combined rows
#define BROWS 64
#define CAPE 1024                 // pass-B per-batch LDS edge capacity
#define CHUNK_A 8192              // pass-A edges per block

typedef __attribute__((ext_vector_type(8))) short bf16x8;
typedef __attribute__((ext_vector_type(4))) float f32x4;

__device__ inline unsigned short bfr(float x) {          // f32 -> bf16 RNE
    unsigned b = __float_as_uint(x);
    b += 0x7FFFu + ((b >> 16) & 1u);
    return (unsigned short)(b >> 16);
}
__device__ inline float bf_lo(unsigned u) { return __uint_as_float(u << 16); }
__device__ inline float bf_hi(unsigned u) { return __uint_as_float(u & 0xFFFF0000u); }

// ================= pack kernels =================

__global__ __launch_bounds__(256) void cvt_x(const float* __restrict__ x, short* __restrict__ A)
{
    int gid = blockIdx.x * 256 + threadIdx.x;
    if (gid >= N_NODES * 32) return;
    int row = gid >> 5, c4 = gid & 31;
    float4 v = *reinterpret_cast<const float4*>(x + (size_t)row * D + c4 * 4);
    ushort4 o = { bfr(v.x), bfr(v.y), bfr(v.z), bfr(v.w) };
    *reinterpret_cast<ushort4*>(A + (size_t)row * KA + c4 * 4) = o;
}

__global__ __launch_bounds__(384) void cvt_w(
    const float* __restrict__ Ws, const float* __restrict__ Wi,
    const float* __restrict__ Wo, short* __restrict__ Wc)
{
    int j = blockIdx.x, k = threadIdx.x;
    float v = (k < 128) ? Ws[j * 128 + k]
            : (k < 256) ? Wi[j * 128 + k - 128]
                        : Wo[j * 128 + k - 256];
    Wc[j * KA + k] = (short)bfr(v);
}

// ================= bucket CSR build =================

// Count edges per 64-row bucket (LDS pre-aggregation).
__global__ __launch_bounds__(1024) void bucket_hist(
    const int* __restrict__ ir, const int* __restrict__ orow, int* __restrict__ bcnt)
{
    __shared__ int h[NB];
    for (int i = threadIdx.x; i < NB; i += 1024) h[i] = 0;
    __syncthreads();
    int stride = gridDim.x * 1024;
    for (int e = blockIdx.x * 1024 + threadIdx.x; e < NE2; e += stride) {
        int r = (e < N_EDGES) ? ir[e] : N_NODES + orow[e - N_EDGES];
        atomicAdd(&h[r >> 6], 1);
    }
    __syncthreads();
    for (int i = threadIdx.x; i < NB; i += 1024)
        if (h[i]) atomicAdd(&bcnt[i], h[i]);
}

// Exclusive scan of NB bucket counts (2 elems/thread) -> bbase, bcur.
__global__ __launch_bounds__(1024) void scan_buckets(
    const int* __restrict__ bcnt, int* __restrict__ bbase, int* __restrict__ bcur)
{
    __shared__ int s[1024];
    const int t = threadIdx.x;
    const int i0 = 2 * t, i1 = 2 * t + 1;
    int v0 = (i0 < NB) ? bcnt[i0] : 0;
    int v1 = (i1 < NB) ? bcnt[i1] : 0;
    int v = v0 + v1;
    s[t] = v;
    __syncthreads();
    for (int o = 1; o < 1024; o <<= 1) {
        int u = (t >= o) ? s[t - o] : 0;
        __syncthreads();
        s[t] += u;
        __syncthreads();
    }
    int ex = s[t] - v;
    if (i0 < NB) { bbase[i0] = ex;      bcur[i0] = ex; }
    if (i1 < NB) { bbase[i1] = ex + v0; bcur[i1] = ex + v0; }
}

// Pass A: bucket-sort edges with block-level reservations (write-local).
// pairp[pos] = { col | (row&63)<<16 , val }
__global__ __launch_bounds__(1024) void scatter_buckets(
    const int* __restrict__ ir, const int* __restrict__ icol, const float* __restrict__ ival,
    const int* __restrict__ orow, const int* __restrict__ ocol, const float* __restrict__ oval,
    int* __restrict__ bcur, int2* __restrict__ pairp)
{
    __shared__ int hist[NB];
    __shared__ int cur[NB];
    const int t = threadIdx.x;
    for (int i = t; i < NB; i += 1024) hist[i] = 0;
    __syncthreads();

    const int e0 = blockIdx.x * CHUNK_A;
    int rr[8], cc[8]; float vv[8];
#pragma unroll
    for (int i = 0; i < 8; ++i) {
        int e = e0 + t + i * 1024;
        if (e < N_EDGES)      { rr[i] = ir[e];                       cc[i] = icol[e];           vv[i] = ival[e]; }
        else if (e < NE2)     { rr[i] = N_NODES + orow[e - N_EDGES]; cc[i] = ocol[e - N_EDGES]; vv[i] = oval[e - N_EDGES]; }
        else                  { rr[i] = -1; cc[i] = 0; vv[i] = 0.f; }
        if (rr[i] >= 0) atomicAdd(&hist[rr[i] >> 6], 1);
    }
    __syncthreads();
    for (int i = t; i < NB; i += 1024) {
        int c = hist[i];
        cur[i] = c ? atomicAdd(&bcur[i], c) : 0;
    }
    __syncthreads();
#pragma unroll
    for (int i = 0; i < 8; ++i) {
        if (rr[i] < 0) continue;
        int pos = atomicAdd(&cur[rr[i] >> 6], 1);
        pairp[pos] = make_int2((cc[i] & 0xFFFF) | ((rr[i] & 63) << 16), __float_as_int(vv[i]));
    }
}

// Pass B (fused row-sort + gather): one block (256 thr = 4 waves) per 64-row bucket.
// Edges staged via registers -> LDS counting sort (64 counters, single-wave shfl scan),
// then wave w gathers rows [w*16, w*16+16) with 4 loads in flight.
__global__ __launch_bounds__(256) void bucket_spmm(
    const int* __restrict__ bbase, const int* __restrict__ bcnt,
    const int2* __restrict__ pairp, short* __restrict__ A)
{
    __shared__ int2 ed[CAPE];            // 8 KB sorted edges
    __shared__ int  rs[BROWS];
    __shared__ int  rstart[BROWS + 1];
    __shared__ int  rcur[BROWS];

    const int t = threadIdx.x;
    const int b = blockIdx.x;
    const int base = bbase[b];
    const int n = bcnt[b];
    const int w = t >> 6, lane = t & 63;
    const int row0 = w * 16;
    const char* Ab = (const char*)A + lane * 4;

    float ax[16], ay[16];
#pragma unroll
    for (int i = 0; i < 16; ++i) { ax[i] = 0.f; ay[i] = 0.f; }

    for (int s0 = 0; s0 < n; s0 += CAPE) {
        const int m = min(n - s0, CAPE);
        if (t < BROWS) rs[t] = 0;
        __syncthreads();
        // load edges into registers + count local rows
        int2 myp[4];
#pragma unroll
        for (int k = 0; k < 4; ++k) {
            int i = t + k * 256;
            if (i < m) {
                myp[k] = pairp[base + s0 + i];
                atomicAdd(&rs[(myp[k].x >> 16) & 63], 1);
            }
        }
        __syncthreads();
        // single-wave shfl scan of 64 counters
        if (t < 64) {
            int v = rs[t];
            int acc = v;
#pragma unroll
            for (int o = 1; o < 64; o <<= 1) {
                int u = __shfl_up(acc, o);
                if (t >= o) acc += u;
            }
            rstart[t] = acc - v;
            rcur[t]   = acc - v;
            if (t == 63) rstart[64] = acc;
        }
        __syncthreads();
        // place into sorted ed[]
#pragma unroll
        for (int k = 0; k < 4; ++k) {
            int i = t + k * 256;
            if (i < m) {
                int pos = atomicAdd(&rcur[(myp[k].x >> 16) & 63], 1);
                ed[pos] = myp[k];
            }
        }
        __syncthreads();
        // gather: wave w owns rows row0..row0+15; 4 loads in flight
#pragma unroll
        for (int ri = 0; ri < 16; ++ri) {
            const int r = row0 + ri;
            int i = rstart[r];
            const int e2 = rstart[r + 1];
            float lax = ax[ri], lay = ay[ri];
            for (; i + 3 < e2; i += 4) {
                int2 p0 = ed[i], p1 = ed[i + 1], p2 = ed[i + 2], p3 = ed[i + 3];
                unsigned u0 = *(const unsigned*)(Ab + (unsigned)((p0.x & 0xFFFF) * (KA * 2)));
                unsigned u1 = *(const unsigned*)(Ab + (unsigned)((p1.x & 0xFFFF) * (KA * 2)));
                unsigned u2 = *(const unsigned*)(Ab + (unsigned)((p2.x & 0xFFFF) * (KA * 2)));
                unsigned u3 = *(const unsigned*)(Ab + (unsigned)((p3.x & 0xFFFF) * (KA * 2)));
                float v0 = __int_as_float(p0.y), v1 = __int_as_float(p1.y);
                float v2 = __int_as_float(p2.y), v3 = __int_as_float(p3.y);
                lax += v0 * bf_lo(u0) + v1 * bf_lo(u1) + v2 * bf_lo(u2) + v3 * bf_lo(u3);
                lay += v0 * bf_hi(u0) + v1 * bf_hi(u1) + v2 * bf_hi(u2) + v3 * bf_hi(u3);
            }
            for (; i < e2; ++i) {
                int2 p = ed[i];
                float v = __int_as_float(p.y);
                unsigned u = *(const unsigned*)(Ab + (unsigned)((p.x & 0xFFFF) * (KA * 2)));
                lax += v * bf_lo(u);
                lay += v * bf_hi(u);
            }
            ax[ri] = lax; ay[ri] = lay;
        }
        __syncthreads();   // before next batch reuses ed
    }

    // write agg rows (bf16) into A columns [128:256) (in) / [256:384) (out)
    char* Aw = (char*)A;
#pragma unroll
    for (int ri = 0; ri < 16; ++ri) {
        int wv = b * BROWS + row0 + ri;
        if (wv >= NT) continue;
        unsigned o = ((unsigned)bfr(ay[ri]) << 16) | (unsigned)bfr(ax[ri]);
        size_t dst = (wv < N_NODES)
                   ? ((size_t)wv * (KA * 2) + 256 + lane * 4)
                   : ((size_t)(wv - N_NODES) * (KA * 2) + 512 + lane * 4);
        *(unsigned*)(Aw + dst) = o;
    }
}

// ================= MFMA GEMM + bias + LayerNorm + ReLU =================
__global__ __launch_bounds__(512) void gemm_mfma(
    const short* __restrict__ A, const short* __restrict__ Wc,
    const float* __restrict__ b, const float* __restrict__ gamma,
    const float* __restrict__ beta, float* __restrict__ out)
{
    __shared__ short Alds[GBM * KA];     // 48 KB
    __shared__ float red[8][64][2];      // 4 KB
    __shared__ float2 mustd[64];

    const int t = threadIdx.x;
    const int l = t & 63, w = t >> 6;
    const int q = l >> 4, c = l & 15;
    const int base = blockIdx.x * GBM;

    bf16x8 bfrag[12];
    const short* wrow = Wc + (size_t)(w * 16 + c) * KA + q * 8;
#pragma unroll
    for (int s = 0; s < 12; ++s)
        bfrag[s] = *reinterpret_cast<const bf16x8*>(wrow + s * 32);

#pragma unroll
    for (int i = 0; i < 6; ++i) {
        int slot = t + i * 512;
        int row = slot / 48, c16 = slot % 48;
        bf16x8 v = *reinterpret_cast<const bf16x8*>(A + (size_t)(base + row) * KA + c16 * 8);
        *reinterpret_cast<bf16x8*>(&Alds[row * KA + (c16 ^ (row & 7)) * 8]) = v;
    }
    __syncthreads();

    f32x4 acc[4];
#pragma unroll
    for (int rg = 0; rg < 4; ++rg) acc[rg] = (f32x4){0.f, 0.f, 0.f, 0.f};

#pragma unroll
    for (int s = 0; s < 12; ++s) {
#pragma unroll
        for (int rg = 0; rg < 4; ++rg) {
            int row = rg * 16 + c;
            int c16 = (s * 4 + q) ^ (row & 7);
            bf16x8 af = *reinterpret_cast<const bf16x8*>(&Alds[row * KA + c16 * 8]);
            acc[rg] = __builtin_amdgcn_mfma_f32_16x16x32_bf16(af, bfrag[s], acc[rg], 0, 0, 0);
        }
    }

    const float bj = b[w * 16 + c];
    const float gj = gamma[w * 16 + c];
    const float ej = beta[w * 16 + c];

#pragma unroll
    for (int rg = 0; rg < 4; ++rg) {
#pragma unroll
        for (int r = 0; r < 4; ++r) {
            float hv = acc[rg][r] + bj;
            acc[rg][r] = hv;
            float s1 = hv, s2 = hv * hv;
#pragma unroll
            for (int m = 1; m < 16; m <<= 1) {
                s1 += __shfl_xor(s1, m);
                s2 += __shfl_xor(s2, m);
            }
            if (c == 0) {
                int row = rg * 16 + q * 4 + r;
                red[w][row][0] = s1;
                red[w][row][1] = s2;
            }
        }
    }
    __syncthreads();

    if (t < 64) {
        float s1 = 0.f, s2 = 0.f;
#pragma unroll
        for (int ww = 0; ww < 8; ++ww) { s1 += red[ww][t][0]; s2 += red[ww][t][1]; }
        float mu = s1 * (1.f / 128.f);
        float var = s2 * (1.f / 128.f) - mu * mu;
        mustd[t] = make_float2(mu, rsqrtf(var + 1e-5f));
    }
    __syncthreads();

#pragma unroll
    for (int rg = 0; rg < 4; ++rg) {
        int row0 = rg * 16 + q * 4;
        int node0 = base + row0;
#pragma unroll
        for (int r = 0; r < 4; ++r) {
            float2 ms = mustd[row0 + r];
            float y = (acc[rg][r] - ms.x) * ms.y * gj + ej;
            y = fmaxf(y, 0.f);
            if (node0 + r < N_NODES)
                out[(size_t)(node0 + r) * D + w * 16 + c] = y;
        }
    }
}

// ================= fp32 fallback (small ws) =================
__global__ __launch_bounds__(256) void spmm_scatter(
    const int* __restrict__ rows, const int* __restrict__ cols,
    const float* __restrict__ vals, const float* __restrict__ x,
    float* __restrict__ agg, int nE)
{
    int g = blockIdx.x * 256 + threadIdx.x;
    int e = g >> 5;
    if (e >= nE) return;
    int q = g & 31;
    int r = rows[e], c = cols[e];
    float v = vals[e];
    float4 xv = *reinterpret_cast<const float4*>(x + (size_t)c * D + (size_t)q * 4);
    float* ap = agg + (size_t)r * D + (size_t)q * 4;
    atomicAdd(ap + 0, v * xv.x);
    atomicAdd(ap + 1, v * xv.y);
    atomicAdd(ap + 2, v * xv.z);
    atomicAdd(ap + 3, v * xv.w);
}

__global__ __launch_bounds__(256) void gemm_ln_relu(
    const float* __restrict__ x, const float* __restrict__ agg_in,
    const float* __restrict__ agg_out,
    const float* __restrict__ Ws, const float* __restrict__ Wi,
    const float* __restrict__ Wo, const float* __restrict__ b,
    const float* __restrict__ gamma, const float* __restrict__ beta,
    float* __restrict__ out, int n)
{
    __shared__ float4 Wl[D * (D / 4)];
    __shared__ float4 Xl[BM * (D / 4)];

    const int t = threadIdx.x;
    const int l = t & 63;
    const int w = t >> 6;
    const int base = blockIdx.x * BM;
    const int j0 = l, j1 = l + 64;

    float acc0[8], acc1[8];
    const float bj0 = b[j0], bj1 = b[j1];
#pragma unroll
    for (int i = 0; i < 8; ++i) { acc0[i] = bj0; acc1[i] = bj1; }

    const float* srcs[3] = { x, agg_in, agg_out };
    const float* wms[3]  = { Ws, Wi, Wo };

#pragma unroll
    for (int s = 0; s < 3; ++s) {
        const float4* src4 = reinterpret_cast<const float4*>(srcs[s]);
        const float4* w4   = reinterpret_cast<const float4*>(wms[s]);
        __syncthreads();
#pragma unroll
        for (int it = 0; it < 16; ++it) {
            int gi = t + 256 * it;
            int j = gi >> 5, k4 = gi & 31;
            Wl[j * 32 + (k4 ^ (j & 7))] = w4[gi];
        }
#pragma unroll
        for (int it = 0; it < 4; ++it) {
            int gi = t + 256 * it;
            int m = gi >> 5, k4 = gi & 31;
            int node = base + m;
            float4 v = (node < n) ? src4[(size_t)node * 32 + k4]
                                  : make_float4(0.f, 0.f, 0.f, 0.f);
            Xl[m * 32 + k4] = v;
        }
        __syncthreads();

        const int sw = j0 & 7;
#pragma unroll 8
        for (int k4 = 0; k4 < 32; ++k4) {
            float4 w0 = Wl[j0 * 32 + (k4 ^ sw)];
            float4 w1 = Wl[j1 * 32 + (k4 ^ sw)];
#pragma unroll
            for (int i = 0; i < 8; ++i) {
                float4 xv = Xl[(w + 4 * i) * 32 + k4];
                acc0[i] += xv.x * w0.x + xv.y * w0.y + xv.z * w0.z + xv.w * w0.w;
                acc1[i] += xv.x * w1.x + xv.y * w1.y + xv.z * w1.z + xv.w * w1.w;
            }
        }
    }

    const float g0 = gamma[j0], g1 = gamma[j1];
    const float be0 = beta[j0], be1 = beta[j1];
#pragma unroll
    for (int i = 0; i < 8; ++i) {
        int node = base + w + 4 * i;
        float s  = acc0[i] + acc1[i];
        float ss = acc0[i] * acc0[i] + acc1[i] * acc1[i];
#pragma unroll
        for (int off = 32; off; off >>= 1) {
            s  += __shfl_xor(s, off);
            ss += __shfl_xor(ss, off);
        }
        float mu   = s * (1.0f / D);
        float var  = ss * (1.0f / D) - mu * mu;
        float rstd = rsqrtf(var + 1e-5f);
        if (node < n) {
            float y0 = (acc0[i] - mu) * rstd * g0 + be0;
            float y1 = (acc1[i] - mu) * rstd * g1 + be1;
            out[(size_t)node * D + j0] = fmaxf(y0, 0.f);
            out[(size_t)node * D + j1] = fmaxf(y1, 0.f);
        }
    }
}

extern "C" void kernel_launch(void* const* d_in, const int* in_sizes, int n_in,
                              void* d_out, int out_size, void* d_ws, size_t ws_size,
                              hipStream_t stream) {
    const float* x     = (const float*)d_in[0];
    const int*   ir    = (const int*)  d_in[1];
    const int*   icoln = (const int*)  d_in[2];
    const float* ival  = (const float*)d_in[3];
    const int*   orow  = (const int*)  d_in[4];
    const int*   ocol  = (const int*)  d_in[5];
    const float* oval  = (const float*)d_in[6];
    const float* Ws    = (const float*)d_in[7];
    const float* b     = (const float*)d_in[8];
    const float* Wi    = (const float*)d_in[9];
    const float* Wo    = (const float*)d_in[10];
    const float* gamma = (const float*)d_in[11];
    const float* beta  = (const float*)d_in[12];
    float* out = (float*)d_out;

    // workspace layout
    short* A     = (short*)d_ws;                     // NPAD x 384 bf16 = 38.44 MB
    short* Wc    = A + (size_t)NPAD * KA;            // 128 x 384 bf16
    int*   bcnt  = (int*)(Wc + (size_t)128 * KA);    // NB
    int*   bbase = bcnt + NB;                        // NB
    int*   bcur  = bbase + NB;                       // NB
    int2*  pairp = (int2*)(bcur + NB + ((3 * NB) & 1)); // NE2 int2, 8B aligned
    size_t need  = (size_t)NPAD * KA * 2 + (size_t)128 * KA * 2
                 + (size_t)(3 * NB + 2) * 4 + (size_t)NE2 * 8;

    if (ws_size >= need) {
        hipMemsetAsync(bcnt, 0, NB * sizeof(int), stream);
        hipMemsetAsync(A + (size_t)N_NODES * KA, 0,
                       (size_t)(NPAD - N_NODES) * KA * 2, stream);

        cvt_x<<<(N_NODES * 32 + 255) / 256, 256, 0, stream>>>(x, A);
        cvt_w<<<128, 384, 0, stream>>>(Ws, Wi, Wo, Wc);

        bucket_hist<<<128, 1024, 0, stream>>>(ir, orow, bcnt);
        scan_buckets<<<1, 1024, 0, stream>>>(bcnt, bbase, bcur);
        scatter_buckets<<<(NE2 + CHUNK_A - 1) / CHUNK_A, 1024, 0, stream>>>(
            ir, icoln, ival, orow, ocol, oval, bcur, pairp);
        bucket_spmm<<<NB, 256, 0, stream>>>(bbase, bcnt, pairp, A);

        gemm_mfma<<<NPAD / GBM, 512, 0, stream>>>(A, Wc, b, gamma, beta, out);
    } else {
        float* agg_in  = (float*)d_ws;
        float* agg_out = agg_in + (size_t)N_NODES * D;
        hipMemsetAsync(d_ws, 0, 2 * (size_t)N_NODES * D * sizeof(float), stream);
        const int eblocks = (N_EDGES * 32 + 255) / 256;
        spmm_scatter<<<eblocks, 256, 0, stream>>>(ir, icoln, ival, x, agg_in, N_EDGES);
        spmm_scatter<<<eblocks, 256, 0, stream>>>(orow, ocol, oval, x, agg_out, N_EDGES);
        const int gblocks = (N_NODES + BM - 1) / BM;
        gemm_ln_relu<<<gblocks, 256, 0, stream>>>(x, agg_in, agg_out, Ws, Wi, Wo,
                                                  b, gamma, beta, out, N_NODES);
    }
}

// Round 7
// 137.875 us; speedup vs baseline: 15.8951x; 1.0554x over previous
//
#include <hip/hip_runtime.h>

#define N_NODES 50000
#define N_EDGES 600000
#define D 128
#define BM 32
#define NT (2 * N_NODES)          // 100000 combined rows (in | out)
#define NE2 (2 * N_EDGES)         // 1200000 combined edges
#define NPAD 50048                // 782 * 64
#define KA 384                    // packed A columns: x | agg_in | agg_out
#define GBM 64                    // gemm M-tile
#define NB 1563                   // buckets of 64 combined rows
#define BROWS 64
#define CAPE 1024                 // pass-B per-batch LDS edge capacity
#define CHUNK_A 8192              // pass-A edges per block

typedef __attribute__((ext_vector_type(8))) short bf16x8;
typedef __attribute__((ext_vector_type(4))) float f32x4;

__device__ inline unsigned short bfr(float x) {          // f32 -> bf16 RNE
    unsigned b = __float_as_uint(x);
    b += 0x7FFFu + ((b >> 16) & 1u);
    return (unsigned short)(b >> 16);
}
__device__ inline float bf_lo(unsigned u) { return __uint_as_float(u << 16); }
__device__ inline float bf_hi(unsigned u) { return __uint_as_float(u & 0xFFFF0000u); }

// ================= pack kernels =================

__global__ __launch_bounds__(256) void cvt_x(const float* __restrict__ x, short* __restrict__ A)
{
    int gid = blockIdx.x * 256 + threadIdx.x;
    if (gid >= N_NODES * 32) return;
    int row = gid >> 5, c4 = gid & 31;
    float4 v = *reinterpret_cast<const float4*>(x + (size_t)row * D + c4 * 4);
    ushort4 o = { bfr(v.x), bfr(v.y), bfr(v.z), bfr(v.w) };
    *reinterpret_cast<ushort4*>(A + (size_t)row * KA + c4 * 4) = o;
}

__global__ __launch_bounds__(384) void cvt_w(
    const float* __restrict__ Ws, const float* __restrict__ Wi,
    const float* __restrict__ Wo, short* __restrict__ Wc)
{
    int j = blockIdx.x, k = threadIdx.x;
    float v = (k < 128) ? Ws[j * 128 + k]
            : (k < 256) ? Wi[j * 128 + k - 128]
                        : Wo[j * 128 + k - 256];
    Wc[j * KA + k] = (short)bfr(v);
}

// ================= bucket CSR build =================

__global__ __launch_bounds__(1024) void bucket_hist(
    const int* __restrict__ ir, const int* __restrict__ orow, int* __restrict__ bcnt)
{
    __shared__ int h[NB];
    for (int i = threadIdx.x; i < NB; i += 1024) h[i] = 0;
    __syncthreads();
    int stride = gridDim.x * 1024;
    for (int e = blockIdx.x * 1024 + threadIdx.x; e < NE2; e += stride) {
        int r = (e < N_EDGES) ? ir[e] : N_NODES + orow[e - N_EDGES];
        atomicAdd(&h[r >> 6], 1);
    }
    __syncthreads();
    for (int i = threadIdx.x; i < NB; i += 1024)
        if (h[i]) atomicAdd(&bcnt[i], h[i]);
}

__global__ __launch_bounds__(1024) void scan_buckets(
    const int* __restrict__ bcnt, int* __restrict__ bbase, int* __restrict__ bcur)
{
    __shared__ int s[1024];
    const int t = threadIdx.x;
    const int i0 = 2 * t, i1 = 2 * t + 1;
    int v0 = (i0 < NB) ? bcnt[i0] : 0;
    int v1 = (i1 < NB) ? bcnt[i1] : 0;
    int v = v0 + v1;
    s[t] = v;
    __syncthreads();
    for (int o = 1; o < 1024; o <<= 1) {
        int u = (t >= o) ? s[t - o] : 0;
        __syncthreads();
        s[t] += u;
        __syncthreads();
    }
    int ex = s[t] - v;
    if (i0 < NB) { bbase[i0] = ex;      bcur[i0] = ex; }
    if (i1 < NB) { bbase[i1] = ex + v0; bcur[i1] = ex + v0; }
}

// Pass A: LDS counting-sort per 8192-edge chunk -> linear coalesced writes.
// pairp[pos] = { col | (row&63)<<16 , val }
__global__ __launch_bounds__(1024) void scatter_buckets(
    const int* __restrict__ ir, const int* __restrict__ icol, const float* __restrict__ ival,
    const int* __restrict__ orow, const int* __restrict__ ocol, const float* __restrict__ oval,
    int* __restrict__ bcur, int2* __restrict__ pairp)
{
    __shared__ int2 pay[CHUNK_A];    // 64 KB sorted payloads
    __shared__ int  dstp[CHUNK_A];   // 32 KB global destinations
    __shared__ int  hist[NB];        // counts, then local cursors
    __shared__ int  lofs[NB];        // local exclusive offsets
    __shared__ int  gb2[NB];         // global_base - local_offset
    __shared__ int  sbuf[1024];

    const int t = threadIdx.x;
    for (int i = t; i < NB; i += 1024) hist[i] = 0;
    __syncthreads();

    const int e0 = blockIdx.x * CHUNK_A;
    const int m = min(NE2 - e0, CHUNK_A);
    int rr[8], cc[8]; float vv[8];
#pragma unroll
    for (int i = 0; i < 8; ++i) {
        int e = e0 + t + i * 1024;
        if (e < N_EDGES)      { rr[i] = ir[e];                       cc[i] = icol[e];           vv[i] = ival[e]; }
        else if (e < NE2)     { rr[i] = N_NODES + orow[e - N_EDGES]; cc[i] = ocol[e - N_EDGES]; vv[i] = oval[e - N_EDGES]; }
        else                  { rr[i] = -1; cc[i] = 0; vv[i] = 0.f; }
        if (rr[i] >= 0) atomicAdd(&hist[rr[i] >> 6], 1);
    }
    __syncthreads();

    // block-local exclusive scan of hist -> lofs (2 elems/thread)
    const int i0 = 2 * t, i1 = 2 * t + 1;
    int h0 = (i0 < NB) ? hist[i0] : 0;
    int h1 = (i1 < NB) ? hist[i1] : 0;
    int hv = h0 + h1;
    sbuf[t] = hv;
    __syncthreads();
    for (int o = 1; o < 1024; o <<= 1) {
        int u = (t >= o) ? sbuf[t - o] : 0;
        __syncthreads();
        sbuf[t] += u;
        __syncthreads();
    }
    int ex = sbuf[t] - hv;
    if (i0 < NB) lofs[i0] = ex;
    if (i1 < NB) lofs[i1] = ex + h0;
    __syncthreads();

    // reserve global runs; fold base: dest = gb2[b] + local_sorted_pos
    for (int i = t; i < NB; i += 1024) {
        int c = hist[i];
        int g = c ? atomicAdd(&bcur[i], c) : 0;
        gb2[i] = g - lofs[i];
    }
    __syncthreads();
    for (int i = t; i < NB; i += 1024) hist[i] = lofs[i];   // reset as cursors
    __syncthreads();

    // place into LDS at sorted position
#pragma unroll
    for (int i = 0; i < 8; ++i) {
        if (rr[i] < 0) continue;
        int bk = rr[i] >> 6;
        int s = atomicAdd(&hist[bk], 1);
        pay[s]  = make_int2((cc[i] & 0xFFFF) | ((rr[i] & 63) << 16), __float_as_int(vv[i]));
        dstp[s] = gb2[bk] + s;
    }
    __syncthreads();

    // linear write-out: consecutive lanes -> consecutive dest within runs
    for (int i = t; i < m; i += 1024)
        pairp[dstp[i]] = pay[i];
}

// Pass B (fused row-sort + gather): one block (512 thr = 8 waves) per 64-row bucket.
// Wave w owns rows [w*8, w*8+8). Each wave splits into two 32-lane halves;
// half h processes edge slot i+2k+h, lane sl covers cols [sl*4, sl*4+4).
// Unroll 4 -> 8 edges in flight; tail is branch-free (clamp idx, zero val).
__global__ __launch_bounds__(512) void bucket_spmm(
    const int* __restrict__ bbase, const int* __restrict__ bcnt,
    const int2* __restrict__ pairp, short* __restrict__ A)
{
    __shared__ int2 ed[CAPE];            // 8 KB sorted edges
    __shared__ int  rs[BROWS];
    __shared__ int  rstart[BROWS + 1];
    __shared__ int  rcur[BROWS];

    const int t = threadIdx.x;
    const int b = blockIdx.x;
    const int base = bbase[b];
    const int n = bcnt[b];
    const int w = t >> 6, lane = t & 63;
    const int h = lane >> 5, sl = lane & 31;
    const int row0 = w * 8;
    const char* Ab = (const char*)A + sl * 8;

    float4 acc[8];
#pragma unroll
    for (int i = 0; i < 8; ++i) acc[i] = make_float4(0.f, 0.f, 0.f, 0.f);

    for (int s0 = 0; s0 < n; s0 += CAPE) {
        const int m = min(n - s0, CAPE);
        if (t < BROWS) rs[t] = 0;
        __syncthreads();
        // load edges into registers + count local rows
        int2 myp[2];
#pragma unroll
        for (int k = 0; k < 2; ++k) {
            int i = t + k * 512;
            if (i < m) {
                myp[k] = pairp[base + s0 + i];
                atomicAdd(&rs[(myp[k].x >> 16) & 63], 1);
            }
        }
        __syncthreads();
        // single-wave shfl scan of 64 counters
        if (t < 64) {
            int v = rs[t];
            int a = v;
#pragma unroll
            for (int o = 1; o < 64; o <<= 1) {
                int u = __shfl_up(a, o);
                if (t >= o) a += u;
            }
            rstart[t] = a - v;
            rcur[t]   = a - v;
            if (t == 63) rstart[64] = a;
        }
        __syncthreads();
        // place into sorted ed[]
#pragma unroll
        for (int k = 0; k < 2; ++k) {
            int i = t + k * 512;
            if (i < m) {
                int pos = atomicAdd(&rcur[(myp[k].x >> 16) & 63], 1);
                ed[pos] = myp[k];
            }
        }
        __syncthreads();
        // gather: 8 edge slots per iteration (4 per half-wave), branch-free tail
#pragma unroll
        for (int ri = 0; ri < 8; ++ri) {
            const int r = row0 + ri;
            const int s = rstart[r], e2 = rstart[r + 1];
            float4 a = acc[ri];
            for (int i = s; i < e2; i += 8) {
#pragma unroll
                for (int k = 0; k < 4; ++k) {
                    int idx = i + 2 * k + h;
                    int2 p = ed[min(idx, e2 - 1)];
                    float v = (idx < e2) ? __int_as_float(p.y) : 0.f;
                    uint2 u = *(const uint2*)(Ab + (unsigned)((p.x & 0xFFFF) * (KA * 2)));
                    a.x += v * bf_lo(u.x);
                    a.y += v * bf_hi(u.x);
                    a.z += v * bf_lo(u.y);
                    a.w += v * bf_hi(u.y);
                }
            }
            acc[ri] = a;
        }
        __syncthreads();   // before next batch reuses ed
    }

    // combine halves, write agg rows (bf16) into A cols [128:256) / [256:384)
    char* Aw = (char*)A;
#pragma unroll
    for (int ri = 0; ri < 8; ++ri) {
        float4 a = acc[ri];
        a.x += __shfl_xor(a.x, 32);
        a.y += __shfl_xor(a.y, 32);
        a.z += __shfl_xor(a.z, 32);
        a.w += __shfl_xor(a.w, 32);
        int wv = b * BROWS + row0 + ri;
        if (lane < 32 && wv < NT) {
            uint2 o;
            o.x = ((unsigned)bfr(a.y) << 16) | (unsigned)bfr(a.x);
            o.y = ((unsigned)bfr(a.w) << 16) | (unsigned)bfr(a.z);
            size_t dst = (wv < N_NODES)
                       ? ((size_t)wv * (KA * 2) + 256 + sl * 8)
                       : ((size_t)(wv - N_NODES) * (KA * 2) + 512 + sl * 8);
            *(uint2*)(Aw + dst) = o;
        }
    }
}

// ================= MFMA GEMM + bias + LayerNorm + ReLU =================
__global__ __launch_bounds__(512) void gemm_mfma(
    const short* __restrict__ A, const short* __restrict__ Wc,
    const float* __restrict__ b, const float* __restrict__ gamma,
    const float* __restrict__ beta, float* __restrict__ out)
{
    __shared__ short Alds[GBM * KA];     // 48 KB
    __shared__ float red[8][64][2];      // 4 KB
    __shared__ float2 mustd[64];

    const int t = threadIdx.x;
    const int l = t & 63, w = t >> 6;
    const int q = l >> 4, c = l & 15;
    const int base = blockIdx.x * GBM;

    bf16x8 bfrag[12];
    const short* wrow = Wc + (size_t)(w * 16 + c) * KA + q * 8;
#pragma unroll
    for (int s = 0; s < 12; ++s)
        bfrag[s] = *reinterpret_cast<const bf16x8*>(wrow + s * 32);

#pragma unroll
    for (int i = 0; i < 6; ++i) {
        int slot = t + i * 512;
        int row = slot / 48, c16 = slot % 48;
        bf16x8 v = *reinterpret_cast<const bf16x8*>(A + (size_t)(base + row) * KA + c16 * 8);
        *reinterpret_cast<bf16x8*>(&Alds[row * KA + (c16 ^ (row & 7)) * 8]) = v;
    }
    __syncthreads();

    f32x4 acc[4];
#pragma unroll
    for (int rg = 0; rg < 4; ++rg) acc[rg] = (f32x4){0.f, 0.f, 0.f, 0.f};

#pragma unroll
    for (int s = 0; s < 12; ++s) {
#pragma unroll
        for (int rg = 0; rg < 4; ++rg) {
            int row = rg * 16 + c;
            int c16 = (s * 4 + q) ^ (row & 7);
            bf16x8 af = *reinterpret_cast<const bf16x8*>(&Alds[row * KA + c16 * 8]);
            acc[rg] = __builtin_amdgcn_mfma_f32_16x16x32_bf16(af, bfrag[s], acc[rg], 0, 0, 0);
        }
    }

    const float bj = b[w * 16 + c];
    const float gj = gamma[w * 16 + c];
    const float ej = beta[w * 16 + c];

#pragma unroll
    for (int rg = 0; rg < 4; ++rg) {
#pragma unroll
        for (int r = 0; r < 4; ++r) {
            float hv = acc[rg][r] + bj;
            acc[rg][r] = hv;
            float s1 = hv, s2 = hv * hv;
#pragma unroll
            for (int m = 1; m < 16; m <<= 1) {
                s1 += __shfl_xor(s1, m);
                s2 += __shfl_xor(s2, m);
            }
            if (c == 0) {
                int row = rg * 16 + q * 4 + r;
                red[w][row][0] = s1;
                red[w][row][1] = s2;
            }
        }
    }
    __syncthreads();

    if (t < 64) {
        float s1 = 0.f, s2 = 0.f;
#pragma unroll
        for (int ww = 0; ww < 8; ++ww) { s1 += red[ww][t][0]; s2 += red[ww][t][1]; }
        float mu = s1 * (1.f / 128.f);
        float var = s2 * (1.f / 128.f) - mu * mu;
        mustd[t] = make_float2(mu, rsqrtf(var + 1e-5f));
    }
    __syncthreads();

#pragma unroll
    for (int rg = 0; rg < 4; ++rg) {
        int row0 = rg * 16 + q * 4;
        int node0 = base + row0;
#pragma unroll
        for (int r = 0; r < 4; ++r) {
            float2 ms = mustd[row0 + r];
            float y = (acc[rg][r] - ms.x) * ms.y * gj + ej;
            y = fmaxf(y, 0.f);
            if (node0 + r < N_NODES)
                out[(size_t)(node0 + r) * D + w * 16 + c] = y;
        }
    }
}

// ================= fp32 fallback (small ws) =================
__global__ __launch_bounds__(256) void spmm_scatter(
    const int* __restrict__ rows, const int* __restrict__ cols,
    const float* __restrict__ vals, const float* __restrict__ x,
    float* __restrict__ agg, int nE)
{
    int g = blockIdx.x * 256 + threadIdx.x;
    int e = g >> 5;
    if (e >= nE) return;
    int q = g & 31;
    int r = rows[e], c = cols[e];
    float v = vals[e];
    float4 xv = *reinterpret_cast<const float4*>(x + (size_t)c * D + (size_t)q * 4);
    float* ap = agg + (size_t)r * D + (size_t)q * 4;
    atomicAdd(ap + 0, v * xv.x);
    atomicAdd(ap + 1, v * xv.y);
    atomicAdd(ap + 2, v * xv.z);
    atomicAdd(ap + 3, v * xv.w);
}

__global__ __launch_bounds__(256) void gemm_ln_relu(
    const float* __restrict__ x, const float* __restrict__ agg_in,
    const float* __restrict__ agg_out,
    const float* __restrict__ Ws, const float* __restrict__ Wi,
    const float* __restrict__ Wo, const float* __restrict__ b,
    const float* __restrict__ gamma, const float* __restrict__ beta,
    float* __restrict__ out, int n)
{
    __shared__ float4 Wl[D * (D / 4)];
    __shared__ float4 Xl[BM * (D / 4)];

    const int t = threadIdx.x;
    const int l = t & 63;
    const int w = t >> 6;
    const int base = blockIdx.x * BM;
    const int j0 = l, j1 = l + 64;

    float acc0[8], acc1[8];
    const float bj0 = b[j0], bj1 = b[j1];
#pragma unroll
    for (int i = 0; i < 8; ++i) { acc0[i] = bj0; acc1[i] = bj1; }

    const float* srcs[3] = { x, agg_in, agg_out };
    const float* wms[3]  = { Ws, Wi, Wo };

#pragma unroll
    for (int s = 0; s < 3; ++s) {
        const float4* src4 = reinterpret_cast<const float4*>(srcs[s]);
        const float4* w4   = reinterpret_cast<const float4*>(wms[s]);
        __syncthreads();
#pragma unroll
        for (int it = 0; it < 16; ++it) {
            int gi = t + 256 * it;
            int j = gi >> 5, k4 = gi & 31;
            Wl[j * 32 + (k4 ^ (j & 7))] = w4[gi];
        }
#pragma unroll
        for (int it = 0; it < 4; ++it) {
            int gi = t + 256 * it;
            int m = gi >> 5, k4 = gi & 31;
            int node = base + m;
            float4 v = (node < n) ? src4[(size_t)node * 32 + k4]
                                  : make_float4(0.f, 0.f, 0.f, 0.f);
            Xl[m * 32 + k4] = v;
        }
        __syncthreads();

        const int sw = j0 & 7;
#pragma unroll 8
        for (int k4 = 0; k4 < 32; ++k4) {
            float4 w0 = Wl[j0 * 32 + (k4 ^ sw)];
            float4 w1 = Wl[j1 * 32 + (k4 ^ sw)];
#pragma unroll
            for (int i = 0; i < 8; ++i) {
                float4 xv = Xl[(w + 4 * i) * 32 + k4];
                acc0[i] += xv.x * w0.x + xv.y * w0.y + xv.z * w0.z + xv.w * w0.w;
                acc1[i] += xv.x * w1.x + xv.y * w1.y + xv.z * w1.z + xv.w * w1.w;
            }
        }
    }

    const float g0 = gamma[j0], g1 = gamma[j1];
    const float be0 = beta[j0], be1 = beta[j1];
#pragma unroll
    for (int i = 0; i < 8; ++i) {
        int node = base + w + 4 * i;
        float s  = acc0[i] + acc1[i];
        float ss = acc0[i] * acc0[i] + acc1[i] * acc1[i];
#pragma unroll
        for (int off = 32; off; off >>= 1) {
            s  += __shfl_xor(s, off);
            ss += __shfl_xor(ss, off);
        }
        float mu   = s * (1.0f / D);
        float var  = ss * (1.0f / D) - mu * mu;
        float rstd = rsqrtf(var + 1e-5f);
        if (node < n) {
            float y0 = (acc0[i] - mu) * rstd * g0 + be0;
            float y1 = (acc1[i] - mu) * rstd * g1 + be1;
            out[(size_t)node * D + j0] = fmaxf(y0, 0.f);
            out[(size_t)node * D + j1] = fmaxf(y1, 0.f);
        }
    }
}

extern "C" void kernel_launch(void* const* d_in, const int* in_sizes, int n_in,
                              void* d_out, int out_size, void* d_ws, size_t ws_size,
                              hipStream_t stream) {
    const float* x     = (const float*)d_in[0];
    const int*   ir    = (const int*)  d_in[1];
    const int*   icoln = (const int*)  d_in[2];
    const float* ival  = (const float*)d_in[3];
    const int*   orow  = (const int*)  d_in[4];
    const int*   ocol  = (const int*)  d_in[5];
    const float* oval  = (const float*)d_in[6];
    const float* Ws    = (const float*)d_in[7];
    const float* b     = (const float*)d_in[8];
    const float* Wi    = (const float*)d_in[9];
    const float* Wo    = (const float*)d_in[10];
    const float* gamma = (const float*)d_in[11];
    const float* beta  = (const float*)d_in[12];
    float* out = (float*)d_out;

    // workspace layout
    short* A     = (short*)d_ws;                     // NPAD x 384 bf16 = 38.44 MB
    short* Wc    = A + (size_t)NPAD * KA;            // 128 x 384 bf16
    int*   bcnt  = (int*)(Wc + (size_t)128 * KA);    // NB
    int*   bbase = bcnt + NB;                        // NB
    int*   bcur  = bbase + NB;                       // NB
    int2*  pairp = (int2*)(bcur + NB + ((3 * NB) & 1)); // NE2 int2, 8B aligned
    size_t need  = (size_t)NPAD * KA * 2 + (size_t)128 * KA * 2
                 + (size_t)(3 * NB + 2) * 4 + (size_t)NE2 * 8;

    if (ws_size >= need) {
        hipMemsetAsync(bcnt, 0, NB * sizeof(int), stream);
        hipMemsetAsync(A + (size_t)N_NODES * KA, 0,
                       (size_t)(NPAD - N_NODES) * KA * 2, stream);

        cvt_x<<<(N_NODES * 32 + 255) / 256, 256, 0, stream>>>(x, A);
        cvt_w<<<128, 384, 0, stream>>>(Ws, Wi, Wo, Wc);

        bucket_hist<<<128, 1024, 0, stream>>>(ir, orow, bcnt);
        scan_buckets<<<1, 1024, 0, stream>>>(bcnt, bbase, bcur);
        scatter_buckets<<<(NE2 + CHUNK_A - 1) / CHUNK_A, 1024, 0, stream>>>(
            ir, icoln, ival, orow, ocol, oval, bcur, pairp);
        bucket_spmm<<<NB, 512, 0, stream>>>(bbase, bcnt, pairp, A);

        gemm_mfma<<<NPAD / GBM, 512, 0, stream>>>(A, Wc, b, gamma, beta, out);
    } else {
        float* agg_in  = (float*)d_ws;
        float* agg_out = agg_in + (size_t)N_NODES * D;
        hipMemsetAsync(d_ws, 0, 2 * (size_t)N_NODES * D * sizeof(float), stream);
        const int eblocks = (N_EDGES * 32 + 255) / 256;
        spmm_scatter<<<eblocks, 256, 0, stream>>>(ir, icoln, ival, x, agg_in, N_EDGES);
        spmm_scatter<<<eblocks, 256, 0, stream>>>(orow, ocol, oval, x, agg_out, N_EDGES);
        const int gblocks = (N_NODES + BM - 1) / BM;
        gemm_ln_relu<<<gblocks, 256, 0, stream>>>(x, agg_in, agg_out, Ws, Wi, Wo,
                                                  b, gamma, beta, out, N_NODES);
    }
}

// Round 8
// 134.043 us; speedup vs baseline: 16.3495x; 1.0286x over previous
//
#include <hip/hip_runtime.h>

#define N_NODES 50000
#define N_EDGES 600000
#define D 128
#define BM 32
#define NT (2 * N_NODES)          // 100000 combined rows (in | out)
#define NE2 (2 * N_EDGES)         // 1200000 combined edges
#define NPAD 50048                // 782 * 64
#define KA 384                    // packed A columns: x | agg_in | agg_out
#define GBM 64                    // gemm M-tile
#define NB 3125                   // buckets of 32 combined rows (100000/32)
#define BROWS 32
#define CAPE 1024                 // pass-B per-batch LDS edge capacity
#define CHUNK_A 8192              // pass-A edges per block

typedef __attribute__((ext_vector_type(8))) short bf16x8;
typedef __attribute__((ext_vector_type(4))) float f32x4;

__device__ inline unsigned short bfr(float x) {          // f32 -> bf16 RNE
    unsigned b = __float_as_uint(x);
    b += 0x7FFFu + ((b >> 16) & 1u);
    return (unsigned short)(b >> 16);
}
__device__ inline float bf_lo(unsigned u) { return __uint_as_float(u << 16); }
__device__ inline float bf_hi(unsigned u) { return __uint_as_float(u & 0xFFFF0000u); }

// ================= pack kernels =================

__global__ __launch_bounds__(256) void cvt_x(const float* __restrict__ x, short* __restrict__ A)
{
    int gid = blockIdx.x * 256 + threadIdx.x;
    if (gid >= N_NODES * 32) return;
    int row = gid >> 5, c4 = gid & 31;
    float4 v = *reinterpret_cast<const float4*>(x + (size_t)row * D + c4 * 4);
    ushort4 o = { bfr(v.x), bfr(v.y), bfr(v.z), bfr(v.w) };
    *reinterpret_cast<ushort4*>(A + (size_t)row * KA + c4 * 4) = o;
}

__global__ __launch_bounds__(384) void cvt_w(
    const float* __restrict__ Ws, const float* __restrict__ Wi,
    const float* __restrict__ Wo, short* __restrict__ Wc)
{
    int j = blockIdx.x, k = threadIdx.x;
    float v = (k < 128) ? Ws[j * 128 + k]
            : (k < 256) ? Wi[j * 128 + k - 128]
                        : Wo[j * 128 + k - 256];
    Wc[j * KA + k] = (short)bfr(v);
}

// ================= bucket CSR build =================

__global__ __launch_bounds__(1024) void bucket_hist(
    const int* __restrict__ ir, const int* __restrict__ orow, int* __restrict__ bcnt)
{
    __shared__ int h[NB];
    for (int i = threadIdx.x; i < NB; i += 1024) h[i] = 0;
    __syncthreads();
    int stride = gridDim.x * 1024;
    for (int e = blockIdx.x * 1024 + threadIdx.x; e < NE2; e += stride) {
        int r = (e < N_EDGES) ? ir[e] : N_NODES + orow[e - N_EDGES];
        atomicAdd(&h[r >> 5], 1);
    }
    __syncthreads();
    for (int i = threadIdx.x; i < NB; i += 1024)
        if (h[i]) atomicAdd(&bcnt[i], h[i]);
}

// Exclusive scan of NB bucket counts (4 elems/thread) -> bbase, bcur.
__global__ __launch_bounds__(1024) void scan_buckets(
    const int* __restrict__ bcnt, int* __restrict__ bbase, int* __restrict__ bcur)
{
    __shared__ int s[1024];
    const int t = threadIdx.x;
    int v[4]; int sum = 0;
#pragma unroll
    for (int j = 0; j < 4; ++j) {
        int i = t * 4 + j;
        v[j] = (i < NB) ? bcnt[i] : 0;
        sum += v[j];
    }
    s[t] = sum;
    __syncthreads();
    for (int o = 1; o < 1024; o <<= 1) {
        int u = (t >= o) ? s[t - o] : 0;
        __syncthreads();
        s[t] += u;
        __syncthreads();
    }
    int ex = s[t] - sum;
#pragma unroll
    for (int j = 0; j < 4; ++j) {
        int i = t * 4 + j;
        if (i < NB) { bbase[i] = ex; bcur[i] = ex; }
        ex += v[j];
    }
}

// Pass A: LDS counting-sort per 8192-edge chunk -> linear coalesced writes.
// pairp[pos] = { col | (row&31)<<16 , val }
__global__ __launch_bounds__(1024) void scatter_buckets(
    const int* __restrict__ ir, const int* __restrict__ icol, const float* __restrict__ ival,
    const int* __restrict__ orow, const int* __restrict__ ocol, const float* __restrict__ oval,
    int* __restrict__ bcur, int2* __restrict__ pairp)
{
    __shared__ int2 pay[CHUNK_A];    // 64 KB sorted payloads
    __shared__ int  dstp[CHUNK_A];   // 32 KB global destinations
    __shared__ int  hist[NB];        // counts, then local cursors
    __shared__ int  lofs[NB];        // local exclusive offsets
    __shared__ int  gb2[NB];         // global_base - local_offset
    __shared__ int  sbuf[1024];

    const int t = threadIdx.x;
    for (int i = t; i < NB; i += 1024) hist[i] = 0;
    __syncthreads();

    const int e0 = blockIdx.x * CHUNK_A;
    const int m = min(NE2 - e0, CHUNK_A);
    int rr[8], cc[8]; float vv[8];
#pragma unroll
    for (int i = 0; i < 8; ++i) {
        int e = e0 + t + i * 1024;
        if (e < N_EDGES)      { rr[i] = ir[e];                       cc[i] = icol[e];           vv[i] = ival[e]; }
        else if (e < NE2)     { rr[i] = N_NODES + orow[e - N_EDGES]; cc[i] = ocol[e - N_EDGES]; vv[i] = oval[e - N_EDGES]; }
        else                  { rr[i] = -1; cc[i] = 0; vv[i] = 0.f; }
        if (rr[i] >= 0) atomicAdd(&hist[rr[i] >> 5], 1);
    }
    __syncthreads();

    // block-local exclusive scan of hist -> lofs (4 elems/thread)
    int h4[4]; int hsum = 0;
#pragma unroll
    for (int j = 0; j < 4; ++j) {
        int i = t * 4 + j;
        h4[j] = (i < NB) ? hist[i] : 0;
        hsum += h4[j];
    }
    sbuf[t] = hsum;
    __syncthreads();
    for (int o = 1; o < 1024; o <<= 1) {
        int u = (t >= o) ? sbuf[t - o] : 0;
        __syncthreads();
        sbuf[t] += u;
        __syncthreads();
    }
    int ex = sbuf[t] - hsum;
#pragma unroll
    for (int j = 0; j < 4; ++j) {
        int i = t * 4 + j;
        if (i < NB) lofs[i] = ex;
        ex += h4[j];
    }
    __syncthreads();

    // reserve global runs; fold base: dest = gb2[b] + local_sorted_pos
    for (int i = t; i < NB; i += 1024) {
        int c = hist[i];
        int g = c ? atomicAdd(&bcur[i], c) : 0;
        gb2[i] = g - lofs[i];
    }
    __syncthreads();
    for (int i = t; i < NB; i += 1024) hist[i] = lofs[i];   // reset as cursors
    __syncthreads();

    // place into LDS at sorted position
#pragma unroll
    for (int i = 0; i < 8; ++i) {
        if (rr[i] < 0) continue;
        int bk = rr[i] >> 5;
        int s = atomicAdd(&hist[bk], 1);
        pay[s]  = make_int2((cc[i] & 0xFFFF) | ((rr[i] & 31) << 16), __float_as_int(vv[i]));
        dstp[s] = gb2[bk] + s;
    }
    __syncthreads();

    // linear write-out: consecutive lanes -> consecutive dest within runs
    for (int i = t; i < m; i += 1024)
        pairp[dstp[i]] = pay[i];
}

// Pass B (fused row-sort + gather): one block (256 thr = 4 waves) per 32-row bucket.
// Wave w owns rows [w*8, w*8+8). Half-wave h processes edge slot i+2k+h;
// lane sl covers cols [sl*4, sl*4+4). 16 slots/iter -> 8 loads in flight/lane.
__global__ __launch_bounds__(256) void bucket_spmm(
    const int* __restrict__ bbase, const int* __restrict__ bcnt,
    const int2* __restrict__ pairp, short* __restrict__ A)
{
    __shared__ int2 ed[CAPE];            // 8 KB sorted edges
    __shared__ int  rs[BROWS];
    __shared__ int  rstart[BROWS + 1];
    __shared__ int  rcur[BROWS];

    const int t = threadIdx.x;
    const int b = blockIdx.x;
    const int base = bbase[b];
    const int n = bcnt[b];
    const int w = t >> 6, lane = t & 63;
    const int h = lane >> 5, sl = lane & 31;
    const int row0 = w * 8;
    const char* Ab = (const char*)A + sl * 8;

    float4 acc[8];
#pragma unroll
    for (int i = 0; i < 8; ++i) acc[i] = make_float4(0.f, 0.f, 0.f, 0.f);

    for (int s0 = 0; s0 < n; s0 += CAPE) {
        const int m = min(n - s0, CAPE);
        if (t < BROWS) rs[t] = 0;
        __syncthreads();
        // load edges into registers + count local rows
        int2 myp[4];
#pragma unroll
        for (int k = 0; k < 4; ++k) {
            int i = t + k * 256;
            if (i < m) {
                myp[k] = pairp[base + s0 + i];
                atomicAdd(&rs[(myp[k].x >> 16) & 31], 1);
            }
        }
        __syncthreads();
        // 32-lane shfl scan of 32 counters
        if (t < 32) {
            int v = rs[t];
            int a = v;
#pragma unroll
            for (int o = 1; o < 32; o <<= 1) {
                int u = __shfl_up(a, o);
                if (t >= o) a += u;
            }
            rstart[t] = a - v;
            rcur[t]   = a - v;
            if (t == 31) rstart[32] = a;
        }
        __syncthreads();
        // place into sorted ed[]
#pragma unroll
        for (int k = 0; k < 4; ++k) {
            int i = t + k * 256;
            if (i < m) {
                int pos = atomicAdd(&rcur[(myp[k].x >> 16) & 31], 1);
                ed[pos] = myp[k];
            }
        }
        __syncthreads();
        // gather: 16 edge slots per iteration (8 per half-wave), branch-free tail
#pragma unroll
        for (int ri = 0; ri < 8; ++ri) {
            const int r = row0 + ri;
            const int s = rstart[r], e2 = rstart[r + 1];
            float4 a = acc[ri];
            for (int i = s; i < e2; i += 16) {
#pragma unroll
                for (int k = 0; k < 8; ++k) {
                    int idx = i + 2 * k + h;
                    int2 p = ed[min(idx, e2 - 1)];
                    float v = (idx < e2) ? __int_as_float(p.y) : 0.f;
                    uint2 u = *(const uint2*)(Ab + (unsigned)((p.x & 0xFFFF) * (KA * 2)));
                    a.x += v * bf_lo(u.x);
                    a.y += v * bf_hi(u.x);
                    a.z += v * bf_lo(u.y);
                    a.w += v * bf_hi(u.y);
                }
            }
            acc[ri] = a;
        }
        __syncthreads();   // before next batch reuses ed
    }

    // combine halves, write agg rows (bf16) into A cols [128:256) / [256:384)
    char* Aw = (char*)A;
#pragma unroll
    for (int ri = 0; ri < 8; ++ri) {
        float4 a = acc[ri];
        a.x += __shfl_xor(a.x, 32);
        a.y += __shfl_xor(a.y, 32);
        a.z += __shfl_xor(a.z, 32);
        a.w += __shfl_xor(a.w, 32);
        int wv = b * BROWS + row0 + ri;
        if (lane < 32 && wv < NT) {
            uint2 o;
            o.x = ((unsigned)bfr(a.y) << 16) | (unsigned)bfr(a.x);
            o.y = ((unsigned)bfr(a.w) << 16) | (unsigned)bfr(a.z);
            size_t dst = (wv < N_NODES)
                       ? ((size_t)wv * (KA * 2) + 256 + sl * 8)
                       : ((size_t)(wv - N_NODES) * (KA * 2) + 512 + sl * 8);
            *(uint2*)(Aw + dst) = o;
        }
    }
}

// ================= MFMA GEMM + bias + LayerNorm + ReLU =================
__global__ __launch_bounds__(512) void gemm_mfma(
    const short* __restrict__ A, const short* __restrict__ Wc,
    const float* __restrict__ b, const float* __restrict__ gamma,
    const float* __restrict__ beta, float* __restrict__ out)
{
    __shared__ short Alds[GBM * KA];     // 48 KB
    __shared__ float red[8][64][2];      // 4 KB
    __shared__ float2 mustd[64];

    const int t = threadIdx.x;
    const int l = t & 63, w = t >> 6;
    const int q = l >> 4, c = l & 15;
    const int base = blockIdx.x * GBM;

    bf16x8 bfrag[12];
    const short* wrow = Wc + (size_t)(w * 16 + c) * KA + q * 8;
#pragma unroll
    for (int s = 0; s < 12; ++s)
        bfrag[s] = *reinterpret_cast<const bf16x8*>(wrow + s * 32);

#pragma unroll
    for (int i = 0; i < 6; ++i) {
        int slot = t + i * 512;
        int row = slot / 48, c16 = slot % 48;
        bf16x8 v = *reinterpret_cast<const bf16x8*>(A + (size_t)(base + row) * KA + c16 * 8);
        *reinterpret_cast<bf16x8*>(&Alds[row * KA + (c16 ^ (row & 7)) * 8]) = v;
    }
    __syncthreads();

    f32x4 acc[4];
#pragma unroll
    for (int rg = 0; rg < 4; ++rg) acc[rg] = (f32x4){0.f, 0.f, 0.f, 0.f};

#pragma unroll
    for (int s = 0; s < 12; ++s) {
#pragma unroll
        for (int rg = 0; rg < 4; ++rg) {
            int row = rg * 16 + c;
            int c16 = (s * 4 + q) ^ (row & 7);
            bf16x8 af = *reinterpret_cast<const bf16x8*>(&Alds[row * KA + c16 * 8]);
            acc[rg] = __builtin_amdgcn_mfma_f32_16x16x32_bf16(af, bfrag[s], acc[rg], 0, 0, 0);
        }
    }

    const float bj = b[w * 16 + c];
    const float gj = gamma[w * 16 + c];
    const float ej = beta[w * 16 + c];

#pragma unroll
    for (int rg = 0; rg < 4; ++rg) {
#pragma unroll
        for (int r = 0; r < 4; ++r) {
            float hv = acc[rg][r] + bj;
            acc[rg][r] = hv;
            float s1 = hv, s2 = hv * hv;
#pragma unroll
            for (int m = 1; m < 16; m <<= 1) {
                s1 += __shfl_xor(s1, m);
                s2 += __shfl_xor(s2, m);
            }
            if (c == 0) {
                int row = rg * 16 + q * 4 + r;
                red[w][row][0] = s1;
                red[w][row][1] = s2;
            }
        }
    }
    __syncthreads();

    if (t < 64) {
        float s1 = 0.f, s2 = 0.f;
#pragma unroll
        for (int ww = 0; ww < 8; ++ww) { s1 += red[ww][t][0]; s2 += red[ww][t][1]; }
        float mu = s1 * (1.f / 128.f);
        float var = s2 * (1.f / 128.f) - mu * mu;
        mustd[t] = make_float2(mu, rsqrtf(var + 1e-5f));
    }
    __syncthreads();

#pragma unroll
    for (int rg = 0; rg < 4; ++rg) {
        int row0 = rg * 16 + q * 4;
        int node0 = base + row0;
#pragma unroll
        for (int r = 0; r < 4; ++r) {
            float2 ms = mustd[row0 + r];
            float y = (acc[rg][r] - ms.x) * ms.y * gj + ej;
            y = fmaxf(y, 0.f);
            if (node0 + r < N_NODES)
                out[(size_t)(node0 + r) * D + w * 16 + c] = y;
        }
    }
}

// ================= fp32 fallback (small ws) =================
__global__ __launch_bounds__(256) void spmm_scatter(
    const int* __restrict__ rows, const int* __restrict__ cols,
    const float* __restrict__ vals, const float* __restrict__ x,
    float* __restrict__ agg, int nE)
{
    int g = blockIdx.x * 256 + threadIdx.x;
    int e = g >> 5;
    if (e >= nE) return;
    int q = g & 31;
    int r = rows[e], c = cols[e];
    float v = vals[e];
    float4 xv = *reinterpret_cast<const float4*>(x + (size_t)c * D + (size_t)q * 4);
    float* ap = agg + (size_t)r * D + (size_t)q * 4;
    atomicAdd(ap + 0, v * xv.x);
    atomicAdd(ap + 1, v * xv.y);
    atomicAdd(ap + 2, v * xv.z);
    atomicAdd(ap + 3, v * xv.w);
}

__global__ __launch_bounds__(256) void gemm_ln_relu(
    const float* __restrict__ x, const float* __restrict__ agg_in,
    const float* __restrict__ agg_out,
    const float* __restrict__ Ws, const float* __restrict__ Wi,
    const float* __restrict__ Wo, const float* __restrict__ b,
    const float* __restrict__ gamma, const float* __restrict__ beta,
    float* __restrict__ out, int n)
{
    __shared__ float4 Wl[D * (D / 4)];
    __shared__ float4 Xl[BM * (D / 4)];

    const int t = threadIdx.x;
    const int l = t & 63;
    const int w = t >> 6;
    const int base = blockIdx.x * BM;
    const int j0 = l, j1 = l + 64;

    float acc0[8], acc1[8];
    const float bj0 = b[j0], bj1 = b[j1];
#pragma unroll
    for (int i = 0; i < 8; ++i) { acc0[i] = bj0; acc1[i] = bj1; }

    const float* srcs[3] = { x, agg_in, agg_out };
    const float* wms[3]  = { Ws, Wi, Wo };

#pragma unroll
    for (int s = 0; s < 3; ++s) {
        const float4* src4 = reinterpret_cast<const float4*>(srcs[s]);
        const float4* w4   = reinterpret_cast<const float4*>(wms[s]);
        __syncthreads();
#pragma unroll
        for (int it = 0; it < 16; ++it) {
            int gi = t + 256 * it;
            int j = gi >> 5, k4 = gi & 31;
            Wl[j * 32 + (k4 ^ (j & 7))] = w4[gi];
        }
#pragma unroll
        for (int it = 0; it < 4; ++it) {
            int gi = t + 256 * it;
            int m = gi >> 5, k4 = gi & 31;
            int node = base + m;
            float4 v = (node < n) ? src4[(size_t)node * 32 + k4]
                                  : make_float4(0.f, 0.f, 0.f, 0.f);
            Xl[m * 32 + k4] = v;
        }
        __syncthreads();

        const int sw = j0 & 7;
#pragma unroll 8
        for (int k4 = 0; k4 < 32; ++k4) {
            float4 w0 = Wl[j0 * 32 + (k4 ^ sw)];
            float4 w1 = Wl[j1 * 32 + (k4 ^ sw)];
#pragma unroll
            for (int i = 0; i < 8; ++i) {
                float4 xv = Xl[(w + 4 * i) * 32 + k4];
                acc0[i] += xv.x * w0.x + xv.y * w0.y + xv.z * w0.z + xv.w * w0.w;
                acc1[i] += xv.x * w1.x + xv.y * w1.y + xv.z * w1.z + xv.w * w1.w;
            }
        }
    }

    const float g0 = gamma[j0], g1 = gamma[j1];
    const float be0 = beta[j0], be1 = beta[j1];
#pragma unroll
    for (int i = 0; i < 8; ++i) {
        int node = base + w + 4 * i;
        float s  = acc0[i] + acc1[i];
        float ss = acc0[i] * acc0[i] + acc1[i] * acc1[i];
#pragma unroll
        for (int off = 32; off; off >>= 1) {
            s  += __shfl_xor(s, off);
            ss += __shfl_xor(ss, off);
        }
        float mu   = s * (1.0f / D);
        float var  = ss * (1.0f / D) - mu * mu;
        float rstd = rsqrtf(var + 1e-5f);
        if (node < n) {
            float y0 = (acc0[i] - mu) * rstd * g0 + be0;
            float y1 = (acc1[i] - mu) * rstd * g1 + be1;
            out[(size_t)node * D + j0] = fmaxf(y0, 0.f);
            out[(size_t)node * D + j1] = fmaxf(y1, 0.f);
        }
    }
}

extern "C" void kernel_launch(void* const* d_in, const int* in_sizes, int n_in,
                              void* d_out, int out_size, void* d_ws, size_t ws_size,
                              hipStream_t stream) {
    const float* x     = (const float*)d_in[0];
    const int*   ir    = (const int*)  d_in[1];
    const int*   icoln = (const int*)  d_in[2];
    const float* ival  = (const float*)d_in[3];
    const int*   orow  = (const int*)  d_in[4];
    const int*   ocol  = (const int*)  d_in[5];
    const float* oval  = (const float*)d_in[6];
    const float* Ws    = (const float*)d_in[7];
    const float* b     = (const float*)d_in[8];
    const float* Wi    = (const float*)d_in[9];
    const float* Wo    = (const float*)d_in[10];
    const float* gamma = (const float*)d_in[11];
    const float* beta  = (const float*)d_in[12];
    float* out = (float*)d_out;

    // workspace layout
    short* A     = (short*)d_ws;                     // NPAD x 384 bf16 = 38.44 MB
    short* Wc    = A + (size_t)NPAD * KA;            // 128 x 384 bf16
    int*   bcnt  = (int*)(Wc + (size_t)128 * KA);    // NB
    int*   bbase = bcnt + NB;                        // NB
    int*   bcur  = bbase + NB;                       // NB
    int2*  pairp = (int2*)(bcur + NB + ((3 * NB) & 1)); // NE2 int2, 8B aligned
    size_t need  = (size_t)NPAD * KA * 2 + (size_t)128 * KA * 2
                 + (size_t)(3 * NB + 2) * 4 + (size_t)NE2 * 8;

    if (ws_size >= need) {
        hipMemsetAsync(bcnt, 0, NB * sizeof(int), stream);
        hipMemsetAsync(A + (size_t)N_NODES * KA, 0,
                       (size_t)(NPAD - N_NODES) * KA * 2, stream);

        cvt_x<<<(N_NODES * 32 + 255) / 256, 256, 0, stream>>>(x, A);
        cvt_w<<<128, 384, 0, stream>>>(Ws, Wi, Wo, Wc);

        bucket_hist<<<128, 1024, 0, stream>>>(ir, orow, bcnt);
        scan_buckets<<<1, 1024, 0, stream>>>(bcnt, bbase, bcur);
        scatter_buckets<<<(NE2 + CHUNK_A - 1) / CHUNK_A, 1024, 0, stream>>>(
            ir, icoln, ival, orow, ocol, oval, bcur, pairp);
        bucket_spmm<<<NB, 256, 0, stream>>>(bbase, bcnt, pairp, A);

        gemm_mfma<<<NPAD / GBM, 512, 0, stream>>>(A, Wc, b, gamma, beta, out);
    } else {
        float* agg_in  = (float*)d_ws;
        float* agg_out = agg_in + (size_t)N_NODES * D;
        hipMemsetAsync(d_ws, 0, 2 * (size_t)N_NODES * D * sizeof(float), stream);
        const int eblocks = (N_EDGES * 32 + 255) / 256;
        spmm_scatter<<<eblocks, 256, 0, stream>>>(ir, icoln, ival, x, agg_in, N_EDGES);
        spmm_scatter<<<eblocks, 256, 0, stream>>>(orow, ocol, oval, x, agg_out, N_EDGES);
        const int gblocks = (N_NODES + BM - 1) / BM;
        gemm_ln_relu<<<gblocks, 256, 0, stream>>>(x, agg_in, agg_out, Ws, Wi, Wo,
                                                  b, gamma, beta, out, N_NODES);
    }
}